// Round 15
// baseline (380.431 us; speedup 1.0000x reference)
//
#include <hip/hip_runtime.h>
#include <stdint.h>

typedef unsigned int u32;
typedef unsigned long long u64;
typedef unsigned char u8;
typedef signed char s8;
typedef int v4i __attribute__((ext_vector_type(4)));
typedef int v16i __attribute__((ext_vector_type(16)));

#define TSTEPS 8
#define BATCH 128
#define CH 128
#define NPIX1 784   // 28*28
#define NPIX2 196   // 14*14
#define TB 1024     // TSTEPS*BATCH
#define FC1_OUT 2048
#define FC1_IN 6272 // 128*49
#define FC2_OUT 10

// conv2: 4 signed base-256 digits, scale 2^32
#define W2_DIGITS 4
#define W2_SCALE 4294967296.0               // 2^32
#define W2_INVSCALE 2.3283064365386963e-10  // 2^-32

// fc1: 4 signed base-256 digits, scale 2^33 (|fw1|max~0.11 -> |r|<2^31)
#define FC1_DIGITS 4
#define FC1_KB 196                          // 6272/32
#define FC1_SCALE 8589934592.0              // 2^33
#define FC1_INVSCALE 1.1641532182693481e-10 // 2^-33

#define P1S_PITCH 25216                     // 197 rows x 128 (row 196 = zeros)

typedef __attribute__((address_space(3))) u32 lds_u32;
typedef const __attribute__((address_space(1))) u32 glb_u32;
#define GLOAD16(G, L) __builtin_amdgcn_global_load_lds((glb_u32*)(G), (lds_u32*)(L), 16, 0, 0)

// ---------------------------------------------------------------------------
// K1: conv1+bn1+IF(T=8, const input)+2x2 maxpool -> spike BYTES in k2's
// swizzled layout: p1s[tb][(pix*128+ci) ^ ((pix&7)<<4)] = 0/1.
// ---------------------------------------------------------------------------
__global__ __launch_bounds__(256) void k1_conv1_if_pool(
    const float* __restrict__ x, const float* __restrict__ w1,
    const float* __restrict__ g1, const float* __restrict__ b1,
    const float* __restrict__ m1, const float* __restrict__ v1,
    u8* __restrict__ p1s)
{
    int bx = blockIdx.x;          // 512 = b*4 + cg
    int b = bx >> 2, cg = bx & 3;
    int tid = threadIdx.x;

    __shared__ float xs[NPIX1];
    __shared__ double wt[32][13];
    __shared__ u8 sbits[NPIX1 * 32];

    for (int i = tid; i < NPIX1; i += 256) xs[i] = x[(size_t)b * NPIX1 + i];
    if (tid < 32) {
        int co = cg * 32 + tid;
#pragma unroll
        for (int k = 0; k < 9; ++k) wt[tid][k] = (double)w1[co * 9 + k];
        double inv = (double)g1[co] / sqrt((double)v1[co] + 1e-5);
        wt[tid][9]  = inv;
        wt[tid][10] = (double)b1[co] - (double)m1[co] * inv;
    }
    __syncthreads();

    for (int i = tid; i < NPIX1 * 32; i += 256) {
        int co = i & 31, p = i >> 5;
        int y = p / 28, xx = p - y * 28;
        double acc = 0.0;
#pragma unroll
        for (int dy = 0; dy < 3; ++dy) {
            int iy = y + dy - 1;
#pragma unroll
            for (int dx = 0; dx < 3; ++dx) {
                int ix = xx + dx - 1;
                if (iy >= 0 && iy < 28 && ix >= 0 && ix < 28)
                    acc += (double)xs[iy * 28 + ix] * wt[co][dy * 3 + dx];
            }
        }
        double yv = acc * wt[co][9] + wt[co][10];
        double v = 0.0; u32 byte = 0;
#pragma unroll
        for (int t = 0; t < 8; ++t) {
            double h = v + yv;
            int s = (h >= 1.0);
            byte |= (u32)s << t;
            v = s ? 0.0 : h;
        }
        sbits[p * 32 + co] = (u8)byte;
    }
    __syncthreads();

    for (int i = tid; i < NPIX2 * 32; i += 256) {
        int co = i & 31, p14 = i >> 5;
        int y14 = p14 / 14, x14 = p14 - y14 * 14;
        int p0 = (2 * y14) * 28 + 2 * x14;
        u8 pv = sbits[p0 * 32 + co] | sbits[(p0 + 1) * 32 + co]
              | sbits[(p0 + 28) * 32 + co] | sbits[(p0 + 29) * 32 + co];
        int off = (p14 * 128 + cg * 32 + co) ^ ((p14 & 7) << 4);
#pragma unroll
        for (int t = 0; t < 8; ++t)
            p1s[(size_t)(t * BATCH + b) * P1S_PITCH + off] = (u8)((pv >> t) & 1);
    }
}

// ---------------------------------------------------------------------------
// K2w: quantize conv2 weights to 4 signed base-256 digits at scale 2^32.
// Fragment-order: Bt[(((d*9+tap)*4+ks)*4+Nt)*1024 + l*16 + bp]
// ---------------------------------------------------------------------------
__global__ __launch_bounds__(256) void k2w_quant(
    const float* __restrict__ w2, s8* __restrict__ Bt)
{
    int g = blockIdx.x * 256 + threadIdx.x;   // co*128+ci
    if (g >= CH * CH) return;
    int co = g >> 7, ci = g & 127;
    int ks = ci >> 5, rem = ci & 31, half = rem >> 4, bp = rem & 15;
    int l = (co & 31) | (half << 5);
    int Nt = co >> 5;
#pragma unroll
    for (int k = 0; k < 9; ++k) {
        double wd = (double)w2[(size_t)g * 9 + k] * W2_SCALE;
        long r = (long)llrint(wd);
#pragma unroll
        for (int d = 0; d < W2_DIGITS; ++d) {
            int dg = (int)(((r + 128) & 255) - 128);
            r = (r - (long)dg) >> 8;
            Bt[((size_t)(((d * 9 + k) * 4 + ks) * 4 + Nt)) * 1024 + l * 16 + bp] = (s8)dg;
        }
    }
}

// ---------------------------------------------------------------------------
// K2: FUSED conv2+bn2+IF2+pool. 256 thr = 4 waves x 2 M-tiles (tiles w, w+4).
// Half-slab DOUBLE buffer (2 x 18KB: 9 taps x 2 digits) -> staging fully
// overlaps compute; LDS 67KB -> 2 blocks/CU. A read on-the-fly per tap
// (no A-cache -> no r12-style spill). Per ks: ph0 {stage d23->buf1, compute
// d01 from buf0}, bar; ph1 {stage next-ks d01->buf0, compute d23 from buf1},
// bar. Packed addresses comb ^ K (verified r14). Exact i64 merge per t.
// ---------------------------------------------------------------------------
__global__ __launch_bounds__(256, 2) void k2_conv2_if_pool(
    const u8* __restrict__ p1s, const s8* __restrict__ Bt,
    const float* __restrict__ g2, const float* __restrict__ bb2,
    const float* __restrict__ m2, const float* __restrict__ v2,
    u8* __restrict__ z2)
{
    int bx = blockIdx.x;          // 512 = b*4 + cq
    int b = bx >> 2, cq = bx & 3;

    int tid = threadIdx.x;
    int lane = tid & 63;
    int lane32 = lane & 31;
    int khalf = (lane >> 5) << 4;
    int w = __builtin_amdgcn_readfirstlane(tid >> 6);  // wave 0..3
    int rhi = (lane >> 5) * 4;

    __shared__ u8 sp[P1S_PITCH];        // 24.6 KB, swizzled
    __shared__ u8 bbuf[2][18432];       // 2 x 18 KB half-slabs
    __shared__ u8 sbuf[NPIX2 * 32];     // 6.3 KB pooling

    // zero the dummy row 196 (never rewritten)
    if (tid < 8) *(uint4*)(sp + 196 * 128 + tid * 16) = make_uint4(0u, 0u, 0u, 0u);

    // bn2 constants (co = cq*32 + lane32)
    int co = cq * 32 + lane32;
    double binv  = (double)g2[co] / sqrt((double)v2[co] + 1e-5);
    double bbeta = (double)bb2[co] - (double)m2[co] * binv;

    // packed per-lane tap addresses for the wave's 2 tiles (196 = zero row)
    int comb[2][9];
#pragma unroll
    for (int m = 0; m < 2; ++m) {
        int tile = w + m * 4;
        int p = tile * 32 + lane32;
        int valid = (p < NPIX2);
        int pe = valid ? p : 0;
        int py = pe / 14, px = pe - py * 14;
#pragma unroll
        for (int tap = 0; tap < 9; ++tap) {
            int dy = tap / 3 - 1, dx = tap - (tap / 3) * 3 - 1;
            int ny = py + dy, nx = px + dx;
            int ok = valid & (ny >= 0) & (ny < 14) & (nx >= 0) & (nx < 14);
            int pixn = ok ? (ny * 14 + nx) : 196;
            comb[m][tap] = pixn * 128 + ((pixn & 7) << 4);
        }
    }

    // stage half-slab (ks, dh) -> bbuf[buf]; frag j = tap*2 + (d - dh*2)
    auto stageB = [&](int ks, int dh, int buf) {
#pragma unroll
        for (int i = 0; i < 5; ++i) {
            int j = w + i * 4;        // 0..19
            if (j < 18) {
                int tap = j >> 1, d = dh * 2 + (j & 1);
                GLOAD16(Bt + ((size_t)(((d * 9 + tap) * 4 + ks) * 4 + cq)) * 1024 + lane * 16,
                        bbuf[buf] + j * 1024);
            }
        }
    };

    // prologue: t=0 spike plane + (ks0, d01) -> buf0
    {
        const u8* s0 = p1s + (size_t)b * P1S_PITCH;
        for (int i = tid; i < 1568; i += 256) GLOAD16(s0 + i * 16, sp + i * 16);
        stageB(0, 0, 0);
    }
    __syncthreads();

    double vst[2][16];
#pragma unroll
    for (int m = 0; m < 2; ++m)
#pragma unroll
        for (int r = 0; r < 16; ++r) vst[m][r] = 0.0;

#pragma unroll 1
    for (int t = 0; t < TSTEPS; ++t) {
        v16i acc[2][4];
#pragma unroll
        for (int m = 0; m < 2; ++m)
#pragma unroll
            for (int d = 0; d < 4; ++d)
#pragma unroll
                for (int r = 0; r < 16; ++r) acc[m][d][r] = 0;

#pragma unroll 1
        for (int ks = 0; ks < 4; ++ks) {
            int K = ks * 32 + khalf;

            // phase 0: stage (ks, d23)->buf1; compute d01 from buf0
            stageB(ks, 1, 1);
#pragma unroll
            for (int tap = 0; tap < 9; ++tap) {
                v4i A0 = *(const v4i*)(sp + (comb[0][tap] ^ K));
                v4i A1 = *(const v4i*)(sp + (comb[1][tap] ^ K));
                v4i B0 = *(const v4i*)(bbuf[0] + (tap * 2 + 0) * 1024 + lane * 16);
                v4i B1 = *(const v4i*)(bbuf[0] + (tap * 2 + 1) * 1024 + lane * 16);
                acc[0][0] = __builtin_amdgcn_mfma_i32_32x32x32_i8(A0, B0, acc[0][0], 0, 0, 0);
                acc[1][0] = __builtin_amdgcn_mfma_i32_32x32x32_i8(A1, B0, acc[1][0], 0, 0, 0);
                acc[0][1] = __builtin_amdgcn_mfma_i32_32x32x32_i8(A0, B1, acc[0][1], 0, 0, 0);
                acc[1][1] = __builtin_amdgcn_mfma_i32_32x32x32_i8(A1, B1, acc[1][1], 0, 0, 0);
            }
            __syncthreads();   // buf1 staged; buf0 reads done

            // phase 1: stage (ks+1, d01)->buf0; compute d23 from buf1
            stageB((ks + 1) & 3, 0, 0);
#pragma unroll
            for (int tap = 0; tap < 9; ++tap) {
                v4i A0 = *(const v4i*)(sp + (comb[0][tap] ^ K));
                v4i A1 = *(const v4i*)(sp + (comb[1][tap] ^ K));
                v4i B2 = *(const v4i*)(bbuf[1] + (tap * 2 + 0) * 1024 + lane * 16);
                v4i B3 = *(const v4i*)(bbuf[1] + (tap * 2 + 1) * 1024 + lane * 16);
                acc[0][2] = __builtin_amdgcn_mfma_i32_32x32x32_i8(A0, B2, acc[0][2], 0, 0, 0);
                acc[1][2] = __builtin_amdgcn_mfma_i32_32x32x32_i8(A1, B2, acc[1][2], 0, 0, 0);
                acc[0][3] = __builtin_amdgcn_mfma_i32_32x32x32_i8(A0, B3, acc[0][3], 0, 0, 0);
                acc[1][3] = __builtin_amdgcn_mfma_i32_32x32x32_i8(A1, B3, acc[1][3], 0, 0, 0);
            }
            __syncthreads();   // buf0 staged for next ks; buf1 free
        }

        // sp reads done; issue next t's spike-plane staging (hidden by epilogue)
        if (t + 1 < TSTEPS) {
            const u8* sn = p1s + (size_t)((t + 1) * BATCH + b) * P1S_PITCH;
            for (int i = tid; i < 1568; i += 256) GLOAD16(sn + i * 16, sp + i * 16);
        }

        // merge digits (exact i64) + bn2 + IF step -> spike bytes
#pragma unroll
        for (int m = 0; m < 2; ++m) {
            int tile = w + m * 4;
#pragma unroll
            for (int r = 0; r < 16; ++r) {
                long carry = ((long)acc[m][3][r] << 24) + ((long)acc[m][2][r] << 16)
                           + ((long)acc[m][1][r] << 8) + (long)acc[m][0][r];
                int pix = tile * 32 + (r & 3) + 8 * (r >> 2) + rhi;
                double hin = (double)carry * W2_INVSCALE * binv + bbeta;
                double hv = vst[m][r] + hin;
                int s = (hv >= 1.0);
                vst[m][r] = s ? 0.0 : hv;
                if (pix < NPIX2) sbuf[pix * 32 + lane32] = (u8)s;
            }
        }
        __syncthreads();

        // 2x2 pool -> z2[kb][tb][32]
        int tb = t * BATCH + b;
        for (int j = tid; j < 49 * 32; j += 256) {
            int w49 = j >> 5, c32 = j & 31;
            int wy = w49 / 7, wx = w49 - wy * 7;
            int p0 = (2 * wy) * 14 + 2 * wx;
            u8 s = sbuf[p0 * 32 + c32] | sbuf[(p0 + 1) * 32 + c32]
                 | sbuf[(p0 + 14) * 32 + c32] | sbuf[(p0 + 15) * 32 + c32];
            int i2 = (cq * 32 + c32) * 49 + w49;
            z2[((size_t)(i2 >> 5) * TB + tb) * 32 + (i2 & 31)] = s;
        }
        __syncthreads();   // drains sp staging before next t's A reads
    }
}

// ---------------------------------------------------------------------------
// K4w: quantize fc1 weights to 4 signed base-256 digits at scale 2^33.
// Layout Wd1[d][kb][o][32] i8.
// ---------------------------------------------------------------------------
__global__ __launch_bounds__(256) void k4w_quant(
    const float* __restrict__ fw, s8* __restrict__ Wd1)
{
    int g = blockIdx.x * 256 + threadIdx.x;   // kb*2048 + o
    if (g >= FC1_KB * FC1_OUT) return;
    int o = g & 2047, kb = g >> 11;

    u32 tmp[FC1_DIGITS][8];
#pragma unroll
    for (int d = 0; d < FC1_DIGITS; ++d)
#pragma unroll
        for (int q = 0; q < 8; ++q) tmp[d][q] = 0;

#pragma unroll
    for (int j = 0; j < 32; ++j) {
        double wd = (double)fw[(size_t)o * FC1_IN + kb * 32 + j] * FC1_SCALE;
        long r = (long)llrint(wd);
#pragma unroll
        for (int d = 0; d < FC1_DIGITS; ++d) {
            int dg = (int)(((r + 128) & 255) - 128);
            r = (r - (long)dg) >> 8;
            tmp[d][j >> 2] |= (u32)(dg & 255) << ((j & 3) * 8);
        }
    }
#pragma unroll
    for (int d = 0; d < FC1_DIGITS; ++d) {
        u32* dst = (u32*)(Wd1 + (((size_t)d * FC1_KB + kb) * FC1_OUT + o) * 32);
        *(uint4*)dst       = make_uint4(tmp[d][0], tmp[d][1], tmp[d][2], tmp[d][3]);
        *(uint4*)(dst + 4) = make_uint4(tmp[d][4], tmp[d][5], tmp[d][6], tmp[d][7]);
    }
}

// ---------------------------------------------------------------------------
// K4: fc1 via i8 MFMA, digit-split -> i32 partials. Grid 256 = mt8 x (nt8 x d4),
// bx = mt*32 + ntd so bx%8 = ntd%8 (same-B blocks colocate per XCD).
// Block 512 thr = 8 waves (2wm x 4wn), tile 128tb x 256o, wave 64x64 (2x2 sub).
// 98 phases x 2kb, 48KB LDS dbuf. Staging source is fragment-order:
// lane l <- row (base + l&31), byte-half (l>>5)*16.
// ---------------------------------------------------------------------------
__global__ __launch_bounds__(512, 2) void k4_fc1_i8(
    const u8* __restrict__ z2, const s8* __restrict__ Wd1,
    int* __restrict__ Hpart)
{
    __shared__ u8 stg[2 * 24576];   // [buf][A 8KB | B 16KB]

    int bx = blockIdx.x;
    int ntd = bx & 31, mt = bx >> 5;
    int nt = ntd >> 2, d = ntd & 3;

    int tid = threadIdx.x;
    int lane = tid & 63, lane32 = lane & 31;
    int half16 = (lane >> 5) << 4;
    int wv = __builtin_amdgcn_readfirstlane(tid >> 6);  // 0..7
    int wm = wv >> 2, wn = wv & 3;

    int tb0 = mt * 128, o0 = nt * 256;

    v16i acc00, acc01, acc10, acc11;
#pragma unroll
    for (int r = 0; r < 16; ++r) { acc00[r] = 0; acc01[r] = 0; acc10[r] = 0; acc11[r] = 0; }

    auto stage = [&](int q, int buf) {
        int kbg0 = q * 2;
        for (int i = wv; i < 24; i += 8) {
            if (i < 8) {
                int kbr = i >> 2, sub = i & 3;
                GLOAD16(z2 + ((size_t)(kbg0 + kbr) * TB + tb0 + sub * 32 + lane32) * 32 + half16,
                        stg + buf * 24576 + i * 1024);
            } else {
                int j = i - 8;
                int kbr = j >> 3, osub = j & 7;
                GLOAD16(Wd1 + (((size_t)d * FC1_KB + kbg0 + kbr) * FC1_OUT + o0 + osub * 32 + lane32) * 32 + half16,
                        stg + buf * 24576 + 8192 + j * 1024);
            }
        }
    };

    stage(0, 0);
    __syncthreads();

#pragma unroll 1
    for (int q = 0; q < 98; ++q) {
        int buf = q & 1;
        if (q + 1 < 98) stage(q + 1, buf ^ 1);
        const u8* A_ = stg + buf * 24576;
        const u8* B_ = A_ + 8192;
#pragma unroll
        for (int kbr = 0; kbr < 2; ++kbr) {
            v4i A0 = *(const v4i*)(A_ + (kbr * 4 + wm * 2 + 0) * 1024 + lane * 16);
            v4i A1 = *(const v4i*)(A_ + (kbr * 4 + wm * 2 + 1) * 1024 + lane * 16);
            v4i B0 = *(const v4i*)(B_ + (kbr * 8 + wn * 2 + 0) * 1024 + lane * 16);
            v4i B1 = *(const v4i*)(B_ + (kbr * 8 + wn * 2 + 1) * 1024 + lane * 16);
            acc00 = __builtin_amdgcn_mfma_i32_32x32x32_i8(A0, B0, acc00, 0, 0, 0);
            acc01 = __builtin_amdgcn_mfma_i32_32x32x32_i8(A0, B1, acc01, 0, 0, 0);
            acc10 = __builtin_amdgcn_mfma_i32_32x32x32_i8(A1, B0, acc10, 0, 0, 0);
            acc11 = __builtin_amdgcn_mfma_i32_32x32x32_i8(A1, B1, acc11, 0, 0, 0);
        }
        __syncthreads();
    }

    int rhi = (lane >> 5) << 2;
    int* Hd = Hpart + (size_t)d * TB * FC1_OUT;
#pragma unroll
    for (int r = 0; r < 16; ++r) {
        int row = (r & 3) + 8 * (r >> 2) + rhi;
        size_t b0 = (size_t)(tb0 + wm * 64 + row) * FC1_OUT + o0 + wn * 64 + lane32;
        Hd[b0]                             = acc00[r];
        Hd[b0 + 32]                        = acc01[r];
        Hd[b0 + (size_t)32 * FC1_OUT]      = acc10[r];
        Hd[b0 + (size_t)32 * FC1_OUT + 32] = acc11[r];
    }
}

// ---------------------------------------------------------------------------
// K5: combine digit partials (exact, c < 2^44) + IF over T -> s3
// ---------------------------------------------------------------------------
__global__ __launch_bounds__(256) void k5_if3(
    const int* __restrict__ Hpart, u8* __restrict__ s3)
{
    int g = blockIdx.x * 256 + threadIdx.x;   // 128*2048
    int b = g >> 11;
    int o = g & 2047;
    double v = 0.0;
#pragma unroll
    for (int t = 0; t < 8; ++t) {
        size_t idx = (size_t)(t * BATCH + b) * FC1_OUT + o;
        long c = 0;
#pragma unroll
        for (int d = 0; d < FC1_DIGITS; ++d)
            c += ((long)Hpart[(size_t)d * TB * FC1_OUT + idx]) << (8 * d);
        double h = v + (double)c * FC1_INVSCALE;
        int s = (h >= 1.0);
        v = s ? 0.0 : h;
        s3[idx] = (u8)s;
    }
}

// ---------------------------------------------------------------------------
// K6: fc2 h4[tb][16] = sum_i s3[tb][i]*fw2[o][i], f64. 256 thr, K-quarters.
// ---------------------------------------------------------------------------
__global__ __launch_bounds__(256) void k6_fc2(
    const u8* __restrict__ s3, const float* __restrict__ fw2,
    double* __restrict__ h4)
{
    int tb = blockIdx.x;
    int tid = threadIdx.x;
    int w = tid >> 6, lane = tid & 63;
    __shared__ double red[4][16];

    double acc[10];
#pragma unroll
    for (int o = 0; o < 10; ++o) acc[o] = 0.0;

#pragma unroll
    for (int it = 0; it < 8; ++it) {
        int i = w * 512 + it * 64 + lane;
        double zd = (double)s3[(size_t)tb * FC1_OUT + i];
#pragma unroll
        for (int o = 0; o < 10; ++o)
            acc[o] += zd * (double)fw2[o * FC1_OUT + i];
    }
#pragma unroll
    for (int o = 0; o < 10; ++o) {
#pragma unroll
        for (int off = 32; off >= 1; off >>= 1)
            acc[o] += __shfl_down(acc[o], off);
    }
    if (lane == 0) {
#pragma unroll
        for (int o = 0; o < 10; ++o) red[w][o] = acc[o];
    }
    __syncthreads();
    if (tid < 10)
        h4[(size_t)tb * 16 + tid] = red[0][tid] + red[1][tid] + red[2][tid] + red[3][tid];
}

// ---------------------------------------------------------------------------
// K7: IF over T on h4 + mean -> out[b][10] f32
// ---------------------------------------------------------------------------
__global__ __launch_bounds__(256) void k7_if4_mean(
    const double* __restrict__ h4, float* __restrict__ out)
{
    int g = blockIdx.x * 256 + threadIdx.x;
    if (g >= BATCH * FC2_OUT) return;
    int b = g / 10;
    int o = g - b * 10;
    double v = 0.0; int cnt = 0;
#pragma unroll
    for (int t = 0; t < 8; ++t) {
        double h = v + h4[(size_t)(t * BATCH + b) * 16 + o];
        int s = (h >= 1.0);
        cnt += s;
        v = s ? 0.0 : h;
    }
    out[b * 10 + o] = (float)cnt * 0.125f;
}

// ---------------------------------------------------------------------------
extern "C" void kernel_launch(void* const* d_in, const int* in_sizes, int n_in,
                              void* d_out, int out_size, void* d_ws, size_t ws_size,
                              hipStream_t stream)
{
    const float* x   = (const float*)d_in[0];
    const float* w1  = (const float*)d_in[1];
    const float* g1  = (const float*)d_in[2];
    const float* b1  = (const float*)d_in[3];
    const float* m1  = (const float*)d_in[4];
    const float* v1  = (const float*)d_in[5];
    const float* w2  = (const float*)d_in[6];
    const float* g2  = (const float*)d_in[7];
    const float* b2  = (const float*)d_in[8];
    const float* m2  = (const float*)d_in[9];
    const float* v2  = (const float*)d_in[10];
    const float* fw1 = (const float*)d_in[11];
    const float* fw2 = (const float*)d_in[12];
    float* out = (float*)d_out;

    char* ws = (char*)d_ws;
    size_t off = 0;
    auto alloc = [&](size_t sz) { size_t o = off; off = (off + sz + 255) & ~(size_t)255; return o; };

    size_t o_p1 = alloc((size_t)TB * P1S_PITCH);                         // 25.8 MB
    size_t o_z  = alloc((size_t)TB * FC1_IN);                            // 6.4 MB
    size_t o_s3 = alloc((size_t)TB * FC1_OUT);                           // 2.1 MB
    size_t o_h4 = alloc((size_t)TB * 16 * 8);                            // 128 KB
    size_t o_wd = alloc((size_t)W2_DIGITS * 9 * CH * CH);                // 590 KB
    size_t o_w1 = alloc((size_t)FC1_DIGITS * FC1_KB * FC1_OUT * 32);     // 51.4 MB
    size_t o_hp = alloc((size_t)FC1_DIGITS * TB * FC1_OUT * 4);          // 33.6 MB
    (void)ws_size;

    u8*     p1s    = (u8*)(ws + o_p1);
    u8*     z2     = (u8*)(ws + o_z);
    u8*     s3     = (u8*)(ws + o_s3);
    double* h4     = (double*)(ws + o_h4);
    s8*     Bt     = (s8*)(ws + o_wd);
    s8*     Wd1    = (s8*)(ws + o_w1);
    int*    Hpart  = (int*)(ws + o_hp);

    k2w_quant<<<dim3((CH * CH + 255) / 256), dim3(256), 0, stream>>>(w2, Bt);

    k4w_quant<<<dim3((FC1_KB * FC1_OUT + 255) / 256), dim3(256), 0, stream>>>(
        fw1, Wd1);

    k1_conv1_if_pool<<<dim3(512), dim3(256), 0, stream>>>(
        x, w1, g1, b1, m1, v1, p1s);

    k2_conv2_if_pool<<<dim3(512), dim3(256), 0, stream>>>(
        p1s, Bt, g2, b2, m2, v2, z2);

    k4_fc1_i8<<<dim3(256), dim3(512), 0, stream>>>(z2, Wd1, Hpart);

    k5_if3<<<dim3(BATCH * FC1_OUT / 256), dim3(256), 0, stream>>>(Hpart, s3);

    k6_fc2<<<dim3(TB), dim3(256), 0, stream>>>(s3, fw2, h4);

    k7_if4_mean<<<dim3((BATCH * FC2_OUT + 255) / 256), dim3(256), 0, stream>>>(h4, out);
}

// Round 16
// 366.347 us; speedup vs baseline: 1.0384x; 1.0384x over previous
//
#include <hip/hip_runtime.h>
#include <stdint.h>

typedef unsigned int u32;
typedef unsigned long long u64;
typedef unsigned char u8;
typedef signed char s8;
typedef int v4i __attribute__((ext_vector_type(4)));
typedef int v16i __attribute__((ext_vector_type(16)));

#define TSTEPS 8
#define BATCH 128
#define CH 128
#define NPIX1 784   // 28*28
#define NPIX2 196   // 14*14
#define TB 1024     // TSTEPS*BATCH
#define FC1_OUT 2048
#define FC1_IN 6272 // 128*49
#define FC2_OUT 10

// conv2: 4 signed base-256 digits, scale 2^32
#define W2_DIGITS 4
#define W2_SCALE 4294967296.0               // 2^32
#define W2_INVSCALE 2.3283064365386963e-10  // 2^-32

// fc1: 4 signed base-256 digits, scale 2^33
#define FC1_DIGITS 4
#define FC1_KB 196                          // 6272/32
#define FC1_SCALE 8589934592.0              // 2^33
#define FC1_INVSCALE 1.1641532182693481e-10 // 2^-33

#define P1S_PITCH 25216                     // 197 rows x 128 (row 196 = zeros)

typedef __attribute__((address_space(3))) u32 lds_u32;
typedef const __attribute__((address_space(1))) u32 glb_u32;
#define GLOAD16(G, L) __builtin_amdgcn_global_load_lds((glb_u32*)(G), (lds_u32*)(L), 16, 0, 0)

// ---------------------------------------------------------------------------
// K1: conv1+bn1+IF(T=8, const input)+2x2 maxpool -> spike BYTES in k2's
// swizzled layout: p1s[tb][(pix*128+ci) ^ ((pix&7)<<4)] = 0/1.
// ---------------------------------------------------------------------------
__global__ __launch_bounds__(256) void k1_conv1_if_pool(
    const float* __restrict__ x, const float* __restrict__ w1,
    const float* __restrict__ g1, const float* __restrict__ b1,
    const float* __restrict__ m1, const float* __restrict__ v1,
    u8* __restrict__ p1s)
{
    int bx = blockIdx.x;          // 512 = b*4 + cg
    int b = bx >> 2, cg = bx & 3;
    int tid = threadIdx.x;

    __shared__ float xs[NPIX1];
    __shared__ double wt[32][13];
    __shared__ u8 sbits[NPIX1 * 32];

    for (int i = tid; i < NPIX1; i += 256) xs[i] = x[(size_t)b * NPIX1 + i];
    if (tid < 32) {
        int co = cg * 32 + tid;
#pragma unroll
        for (int k = 0; k < 9; ++k) wt[tid][k] = (double)w1[co * 9 + k];
        double inv = (double)g1[co] / sqrt((double)v1[co] + 1e-5);
        wt[tid][9]  = inv;
        wt[tid][10] = (double)b1[co] - (double)m1[co] * inv;
    }
    __syncthreads();

    for (int i = tid; i < NPIX1 * 32; i += 256) {
        int co = i & 31, p = i >> 5;
        int y = p / 28, xx = p - y * 28;
        double acc = 0.0;
#pragma unroll
        for (int dy = 0; dy < 3; ++dy) {
            int iy = y + dy - 1;
#pragma unroll
            for (int dx = 0; dx < 3; ++dx) {
                int ix = xx + dx - 1;
                if (iy >= 0 && iy < 28 && ix >= 0 && ix < 28)
                    acc += (double)xs[iy * 28 + ix] * wt[co][dy * 3 + dx];
            }
        }
        double yv = acc * wt[co][9] + wt[co][10];
        double v = 0.0; u32 byte = 0;
#pragma unroll
        for (int t = 0; t < 8; ++t) {
            double h = v + yv;
            int s = (h >= 1.0);
            byte |= (u32)s << t;
            v = s ? 0.0 : h;
        }
        sbits[p * 32 + co] = (u8)byte;
    }
    __syncthreads();

    for (int i = tid; i < NPIX2 * 32; i += 256) {
        int co = i & 31, p14 = i >> 5;
        int y14 = p14 / 14, x14 = p14 - y14 * 14;
        int p0 = (2 * y14) * 28 + 2 * x14;
        u8 pv = sbits[p0 * 32 + co] | sbits[(p0 + 1) * 32 + co]
              | sbits[(p0 + 28) * 32 + co] | sbits[(p0 + 29) * 32 + co];
        int off = (p14 * 128 + cg * 32 + co) ^ ((p14 & 7) << 4);
#pragma unroll
        for (int t = 0; t < 8; ++t)
            p1s[(size_t)(t * BATCH + b) * P1S_PITCH + off] = (u8)((pv >> t) & 1);
    }
}

// ---------------------------------------------------------------------------
// K2w: quantize conv2 weights to 4 signed base-256 digits at scale 2^32.
// Fragment-order: Bt[(((d*9+tap)*4+ks)*4+Nt)*1024 + l*16 + bp]
// ---------------------------------------------------------------------------
__global__ __launch_bounds__(256) void k2w_quant(
    const float* __restrict__ w2, s8* __restrict__ Bt)
{
    int g = blockIdx.x * 256 + threadIdx.x;   // co*128+ci
    if (g >= CH * CH) return;
    int co = g >> 7, ci = g & 127;
    int ks = ci >> 5, rem = ci & 31, half = rem >> 4, bp = rem & 15;
    int l = (co & 31) | (half << 5);
    int Nt = co >> 5;
#pragma unroll
    for (int k = 0; k < 9; ++k) {
        double wd = (double)w2[(size_t)g * 9 + k] * W2_SCALE;
        long r = (long)llrint(wd);
#pragma unroll
        for (int d = 0; d < W2_DIGITS; ++d) {
            int dg = (int)(((r + 128) & 255) - 128);
            r = (r - (long)dg) >> 8;
            Bt[((size_t)(((d * 9 + k) * 4 + ks) * 4 + Nt)) * 1024 + l * 16 + bp] = (s8)dg;
        }
    }
}

// ---------------------------------------------------------------------------
// K2: FUSED conv2+bn2+IF2+pool (r13 shape, proven 185us). 512 thr = 8 waves,
// ONE M-tile per wave. ks-major: A[9] reg cache reused over 4 digits; full
// B slab (36KB, 9tap x 4d) double-buffered via global_load_lds; 1 barrier/ks.
// Exact i64 digit merge per t. LDS 105KB -> 1 block/CU but 2 waves/SIMD.
// ---------------------------------------------------------------------------
__global__ __launch_bounds__(512, 2) void k2_conv2_if_pool(
    const u8* __restrict__ p1s, const s8* __restrict__ Bt,
    const float* __restrict__ g2, const float* __restrict__ bb2,
    const float* __restrict__ m2, const float* __restrict__ v2,
    u8* __restrict__ z2)
{
    int bx = blockIdx.x;          // 512 = b*4 + cq
    int b = bx >> 2, cq = bx & 3;

    int tid = threadIdx.x;
    int lane = tid & 63;
    int lane32 = lane & 31;
    int khalf = (lane >> 5) << 4;
    int w = __builtin_amdgcn_readfirstlane(tid >> 6);  // wave 0..7 = M tile
    int rhi = (lane >> 5) * 4;

    __shared__ u8 sp[P1S_PITCH];        // 197 rows x 128, swizzled (24.6 KB)
    __shared__ u8 bbuf[2][36864];       // B slab dbuf: 9 taps x 4 digits (72 KB)
    __shared__ u8 sbuf[NPIX2 * 32];     // spike bytes for pooling (6.3 KB)

    // zero the dummy row 196 (never rewritten)
    if (tid < 8) *(uint4*)(sp + 196 * 128 + tid * 16) = make_uint4(0u, 0u, 0u, 0u);

    // bn2 constants (co = cq*32 + lane32)
    int co = cq * 32 + lane32;
    double binv  = (double)g2[co] / sqrt((double)v2[co] + 1e-5);
    double bbeta = (double)bb2[co] - (double)m2[co] * binv;

    // per-lane tap neighbor addresses for this wave's tile (196 = zero row)
    int p = w * 32 + lane32;
    int valid = (p < NPIX2);
    int pe = valid ? p : 0;
    int py = pe / 14, px = pe - py * 14;
    int pixb[9], psw[9];
#pragma unroll
    for (int tap = 0; tap < 9; ++tap) {
        int dy = tap / 3 - 1, dx = tap - (tap / 3) * 3 - 1;
        int ny = py + dy, nx = px + dx;
        int ok = valid & (ny >= 0) & (ny < 14) & (nx >= 0) & (nx < 14);
        int pixn = ok ? (ny * 14 + nx) : 196;
        pixb[tap] = pixn * 128;
        psw[tap]  = (pixn & 7) << 4;
    }

    // stage full B slab for k-slice ks -> bbuf[bufsel]: 36 frags over 8 waves
    auto stageB = [&](int ks, int bufsel) {
#pragma unroll
        for (int i = 0; i < 5; ++i) {
            int f = w + i * 8;        // 0..39, f = d*9+tap composite
            if (f < 36) {
                GLOAD16(Bt + ((size_t)((f * 4 + ks) * 4 + cq)) * 1024 + lane * 16,
                        bbuf[bufsel] + f * 1024);
            }
        }
    };

    // prologue: t=0 spike plane + slab ks=0 -> buf 0
    {
        const u8* s0 = p1s + (size_t)b * P1S_PITCH;
        for (int i = tid; i < 1568; i += 512) GLOAD16(s0 + i * 16, sp + i * 16);
        stageB(0, 0);
    }
    __syncthreads();

    double vst[16];
#pragma unroll
    for (int r = 0; r < 16; ++r) vst[r] = 0.0;

#pragma unroll 1
    for (int t = 0; t < TSTEPS; ++t) {
        v16i acc[4];
#pragma unroll
        for (int d = 0; d < 4; ++d)
#pragma unroll
            for (int r = 0; r < 16; ++r) acc[d][r] = 0;

#pragma unroll 1
        for (int ks = 0; ks < 4; ++ks) {
            int cur = ks & 1;
            // prefetch next slab (periodic mod 4; final t's last prefetch harmless)
            stageB((ks + 1) & 3, cur ^ 1);

            // A register cache for this k-slice (static indexing)
            v4i A[9];
#pragma unroll
            for (int tap = 0; tap < 9; ++tap)
                A[tap] = *(const v4i*)(sp + pixb[tap] + ((ks * 32 + khalf) ^ psw[tap]));

            const u8* bbp = bbuf[cur];
#pragma unroll
            for (int d = 0; d < 4; ++d) {
#pragma unroll
                for (int tap = 0; tap < 9; ++tap) {
                    v4i B = *(const v4i*)(bbp + (d * 9 + tap) * 1024 + lane * 16);
                    acc[d] = __builtin_amdgcn_mfma_i32_32x32x32_i8(A[tap], B, acc[d], 0, 0, 0);
                }
            }
            __syncthreads();   // protects bbuf reuse + drains prefetch
        }

        // all sp reads for this t done; stage next t's spike plane
        if (t + 1 < TSTEPS) {
            const u8* sn = p1s + (size_t)((t + 1) * BATCH + b) * P1S_PITCH;
            for (int i = tid; i < 1568; i += 512) GLOAD16(sn + i * 16, sp + i * 16);
        }

        // merge digits (exact i64) + bn2 + IF step -> spike bytes
#pragma unroll
        for (int r = 0; r < 16; ++r) {
            long carry = ((long)acc[3][r] << 24) + ((long)acc[2][r] << 16)
                       + ((long)acc[1][r] << 8) + (long)acc[0][r];
            int pix = w * 32 + (r & 3) + 8 * (r >> 2) + rhi;
            double hin = (double)carry * W2_INVSCALE * binv + bbeta;
            double hv = vst[r] + hin;
            int s = (hv >= 1.0);
            vst[r] = s ? 0.0 : hv;
            if (pix < NPIX2) sbuf[pix * 32 + lane32] = (u8)s;
        }
        __syncthreads();

        // 2x2 pool -> z2[kb][tb][32]
        int tb = t * BATCH + b;
        for (int j = tid; j < 49 * 32; j += 512) {
            int w49 = j >> 5, c32 = j & 31;
            int wy = w49 / 7, wx = w49 - wy * 7;
            int p0 = (2 * wy) * 14 + 2 * wx;
            u8 s = sbuf[p0 * 32 + c32] | sbuf[(p0 + 1) * 32 + c32]
                 | sbuf[(p0 + 14) * 32 + c32] | sbuf[(p0 + 15) * 32 + c32];
            int i2 = (cq * 32 + c32) * 49 + w49;
            z2[((size_t)(i2 >> 5) * TB + tb) * 32 + (i2 & 31)] = s;
        }
        __syncthreads();   // drains sp staging before next t's A reads
    }
}

// ---------------------------------------------------------------------------
// K4w: quantize fc1 weights to 4 signed base-256 digits at scale 2^33.
// Layout Wd1[d][kb][o][32] i8.
// ---------------------------------------------------------------------------
__global__ __launch_bounds__(256) void k4w_quant(
    const float* __restrict__ fw, s8* __restrict__ Wd1)
{
    int g = blockIdx.x * 256 + threadIdx.x;   // kb*2048 + o
    if (g >= FC1_KB * FC1_OUT) return;
    int o = g & 2047, kb = g >> 11;

    u32 tmp[FC1_DIGITS][8];
#pragma unroll
    for (int d = 0; d < FC1_DIGITS; ++d)
#pragma unroll
        for (int q = 0; q < 8; ++q) tmp[d][q] = 0;

#pragma unroll
    for (int j = 0; j < 32; ++j) {
        double wd = (double)fw[(size_t)o * FC1_IN + kb * 32 + j] * FC1_SCALE;
        long r = (long)llrint(wd);
#pragma unroll
        for (int d = 0; d < FC1_DIGITS; ++d) {
            int dg = (int)(((r + 128) & 255) - 128);
            r = (r - (long)dg) >> 8;
            tmp[d][j >> 2] |= (u32)(dg & 255) << ((j & 3) * 8);
        }
    }
#pragma unroll
    for (int d = 0; d < FC1_DIGITS; ++d) {
        u32* dst = (u32*)(Wd1 + (((size_t)d * FC1_KB + kb) * FC1_OUT + o) * 32);
        *(uint4*)dst       = make_uint4(tmp[d][0], tmp[d][1], tmp[d][2], tmp[d][3]);
        *(uint4*)(dst + 4) = make_uint4(tmp[d][4], tmp[d][5], tmp[d][6], tmp[d][7]);
    }
}

// ---------------------------------------------------------------------------
// K4: fc1 via i8 MFMA, digit-split -> i32 partials. Grid 256 = mt8 x (nt8 x d4),
// bx = mt*32 + ntd so bx%8 = ntd%8 (same-B blocks colocate per XCD).
// Block 512 thr = 8 waves (2wm x 4wn), tile 128tb x 256o, wave 64x64 (2x2 sub).
// 98 phases x 2kb, 48KB LDS dbuf. Staging source is fragment-order:
// lane l <- row (base + l&31), byte-half (l>>5)*16.
// ---------------------------------------------------------------------------
__global__ __launch_bounds__(512, 2) void k4_fc1_i8(
    const u8* __restrict__ z2, const s8* __restrict__ Wd1,
    int* __restrict__ Hpart)
{
    __shared__ u8 stg[2 * 24576];   // [buf][A 8KB | B 16KB]

    int bx = blockIdx.x;
    int ntd = bx & 31, mt = bx >> 5;
    int nt = ntd >> 2, d = ntd & 3;

    int tid = threadIdx.x;
    int lane = tid & 63, lane32 = lane & 31;
    int half16 = (lane >> 5) << 4;
    int wv = __builtin_amdgcn_readfirstlane(tid >> 6);  // 0..7
    int wm = wv >> 2, wn = wv & 3;

    int tb0 = mt * 128, o0 = nt * 256;

    v16i acc00, acc01, acc10, acc11;
#pragma unroll
    for (int r = 0; r < 16; ++r) { acc00[r] = 0; acc01[r] = 0; acc10[r] = 0; acc11[r] = 0; }

    auto stage = [&](int q, int buf) {
        int kbg0 = q * 2;
        for (int i = wv; i < 24; i += 8) {
            if (i < 8) {
                int kbr = i >> 2, sub = i & 3;
                GLOAD16(z2 + ((size_t)(kbg0 + kbr) * TB + tb0 + sub * 32 + lane32) * 32 + half16,
                        stg + buf * 24576 + i * 1024);
            } else {
                int j = i - 8;
                int kbr = j >> 3, osub = j & 7;
                GLOAD16(Wd1 + (((size_t)d * FC1_KB + kbg0 + kbr) * FC1_OUT + o0 + osub * 32 + lane32) * 32 + half16,
                        stg + buf * 24576 + 8192 + j * 1024);
            }
        }
    };

    stage(0, 0);
    __syncthreads();

#pragma unroll 1
    for (int q = 0; q < 98; ++q) {
        int buf = q & 1;
        if (q + 1 < 98) stage(q + 1, buf ^ 1);
        const u8* A_ = stg + buf * 24576;
        const u8* B_ = A_ + 8192;
#pragma unroll
        for (int kbr = 0; kbr < 2; ++kbr) {
            v4i A0 = *(const v4i*)(A_ + (kbr * 4 + wm * 2 + 0) * 1024 + lane * 16);
            v4i A1 = *(const v4i*)(A_ + (kbr * 4 + wm * 2 + 1) * 1024 + lane * 16);
            v4i B0 = *(const v4i*)(B_ + (kbr * 8 + wn * 2 + 0) * 1024 + lane * 16);
            v4i B1 = *(const v4i*)(B_ + (kbr * 8 + wn * 2 + 1) * 1024 + lane * 16);
            acc00 = __builtin_amdgcn_mfma_i32_32x32x32_i8(A0, B0, acc00, 0, 0, 0);
            acc01 = __builtin_amdgcn_mfma_i32_32x32x32_i8(A0, B1, acc01, 0, 0, 0);
            acc10 = __builtin_amdgcn_mfma_i32_32x32x32_i8(A1, B0, acc10, 0, 0, 0);
            acc11 = __builtin_amdgcn_mfma_i32_32x32x32_i8(A1, B1, acc11, 0, 0, 0);
        }
        __syncthreads();
    }

    int rhi = (lane >> 5) << 2;
    int* Hd = Hpart + (size_t)d * TB * FC1_OUT;
#pragma unroll
    for (int r = 0; r < 16; ++r) {
        int row = (r & 3) + 8 * (r >> 2) + rhi;
        size_t b0 = (size_t)(tb0 + wm * 64 + row) * FC1_OUT + o0 + wn * 64 + lane32;
        Hd[b0]                             = acc00[r];
        Hd[b0 + 32]                        = acc01[r];
        Hd[b0 + (size_t)32 * FC1_OUT]      = acc10[r];
        Hd[b0 + (size_t)32 * FC1_OUT + 32] = acc11[r];
    }
}

// ---------------------------------------------------------------------------
// K5 FUSED: combine digit partials (exact i64) + IF3 -> s3 in LDS,
// then fc2 (f64, per-wave shuffle reduce) + IF4 + mean -> out[b][10].
// One block per b (128 blocks x 256 thr). Replaces k5+k6+k7.
// ---------------------------------------------------------------------------
__global__ __launch_bounds__(256) void k5_fused(
    const int* __restrict__ Hpart, const float* __restrict__ fw2,
    float* __restrict__ out)
{
    int b = blockIdx.x;
    int tid = threadIdx.x;
    int w = tid >> 6, lane = tid & 63;

    __shared__ u8 s3l[TSTEPS][FC1_OUT];   // 16 KB
    __shared__ double red[TSTEPS][16];    // 1 KB

    // combine + IF3: each thread owns 8 o's (o = tid + q*256, coalesced)
#pragma unroll
    for (int q = 0; q < 8; ++q) {
        int o = tid + q * 256;
        double v = 0.0;
#pragma unroll
        for (int t = 0; t < TSTEPS; ++t) {
            size_t idx = (size_t)(t * BATCH + b) * FC1_OUT + o;
            long c = 0;
#pragma unroll
            for (int d = 0; d < FC1_DIGITS; ++d)
                c += ((long)Hpart[(size_t)d * TB * FC1_OUT + idx]) << (8 * d);
            double h = v + (double)c * FC1_INVSCALE;
            int s = (h >= 1.0);
            v = s ? 0.0 : h;
            s3l[t][o] = (u8)s;
        }
    }
    __syncthreads();

    // fc2 for t = w and t = w+4 (4 waves cover 8 timesteps)
#pragma unroll
    for (int half = 0; half < 2; ++half) {
        int t = w + half * 4;
        double acc[10];
#pragma unroll
        for (int o = 0; o < 10; ++o) acc[o] = 0.0;
        for (int i = lane; i < FC1_OUT; i += 64) {
            double zd = (double)s3l[t][i];
#pragma unroll
            for (int o = 0; o < 10; ++o)
                acc[o] += zd * (double)fw2[o * FC1_OUT + i];
        }
#pragma unroll
        for (int o = 0; o < 10; ++o) {
#pragma unroll
            for (int off = 32; off >= 1; off >>= 1)
                acc[o] += __shfl_down(acc[o], off);
        }
        if (lane == 0) {
#pragma unroll
            for (int o = 0; o < 10; ++o) red[t][o] = acc[o];
        }
    }
    __syncthreads();

    // IF4 + mean
    if (tid < 10) {
        double v = 0.0; int cnt = 0;
#pragma unroll
        for (int t = 0; t < TSTEPS; ++t) {
            double h = v + red[t][tid];
            int s = (h >= 1.0);
            cnt += s;
            v = s ? 0.0 : h;
        }
        out[b * 10 + tid] = (float)cnt * 0.125f;
    }
}

// ---------------------------------------------------------------------------
extern "C" void kernel_launch(void* const* d_in, const int* in_sizes, int n_in,
                              void* d_out, int out_size, void* d_ws, size_t ws_size,
                              hipStream_t stream)
{
    const float* x   = (const float*)d_in[0];
    const float* w1  = (const float*)d_in[1];
    const float* g1  = (const float*)d_in[2];
    const float* b1  = (const float*)d_in[3];
    const float* m1  = (const float*)d_in[4];
    const float* v1  = (const float*)d_in[5];
    const float* w2  = (const float*)d_in[6];
    const float* g2  = (const float*)d_in[7];
    const float* b2  = (const float*)d_in[8];
    const float* m2  = (const float*)d_in[9];
    const float* v2  = (const float*)d_in[10];
    const float* fw1 = (const float*)d_in[11];
    const float* fw2 = (const float*)d_in[12];
    float* out = (float*)d_out;

    char* ws = (char*)d_ws;
    size_t off = 0;
    auto alloc = [&](size_t sz) { size_t o = off; off = (off + sz + 255) & ~(size_t)255; return o; };

    size_t o_p1 = alloc((size_t)TB * P1S_PITCH);                         // 25.8 MB
    size_t o_z  = alloc((size_t)TB * FC1_IN);                            // 6.4 MB
    size_t o_wd = alloc((size_t)W2_DIGITS * 9 * CH * CH);                // 590 KB
    size_t o_w1 = alloc((size_t)FC1_DIGITS * FC1_KB * FC1_OUT * 32);     // 51.4 MB
    size_t o_hp = alloc((size_t)FC1_DIGITS * TB * FC1_OUT * 4);          // 33.6 MB
    (void)ws_size;

    u8*     p1s    = (u8*)(ws + o_p1);
    u8*     z2     = (u8*)(ws + o_z);
    s8*     Bt     = (s8*)(ws + o_wd);
    s8*     Wd1    = (s8*)(ws + o_w1);
    int*    Hpart  = (int*)(ws + o_hp);

    k2w_quant<<<dim3((CH * CH + 255) / 256), dim3(256), 0, stream>>>(w2, Bt);

    k4w_quant<<<dim3((FC1_KB * FC1_OUT + 255) / 256), dim3(256), 0, stream>>>(
        fw1, Wd1);

    k1_conv1_if_pool<<<dim3(512), dim3(256), 0, stream>>>(
        x, w1, g1, b1, m1, v1, p1s);

    k2_conv2_if_pool<<<dim3(512), dim3(512), 0, stream>>>(
        p1s, Bt, g2, b2, m2, v2, z2);

    k4_fc1_i8<<<dim3(256), dim3(512), 0, stream>>>(z2, Wd1, Hpart);

    k5_fused<<<dim3(BATCH), dim3(256), 0, stream>>>(Hpart, fw2, out);
}

// Round 17
// 325.152 us; speedup vs baseline: 1.1700x; 1.1267x over previous
//
#include <hip/hip_runtime.h>
#include <stdint.h>

typedef unsigned int u32;
typedef unsigned long long u64;
typedef unsigned char u8;
typedef signed char s8;
typedef int v4i __attribute__((ext_vector_type(4)));
typedef int v16i __attribute__((ext_vector_type(16)));

#define TSTEPS 8
#define BATCH 128
#define CH 128
#define NPIX1 784   // 28*28
#define NPIX2 196   // 14*14
#define TB 1024     // TSTEPS*BATCH
#define FC1_OUT 2048
#define FC1_IN 6272 // 128*49
#define FC2_OUT 10

// conv2: 4 signed base-256 digits, scale 2^32
#define W2_DIGITS 4
#define W2_SCALE 4294967296.0               // 2^32
#define W2_INVSCALE 2.3283064365386963e-10  // 2^-32

// fc1: 4 signed base-256 digits, scale 2^33
#define FC1_DIGITS 4
#define FC1_KB 196                          // 6272/32
#define FC1_SCALE 8589934592.0              // 2^33
#define FC1_INVSCALE 1.1641532182693481e-10 // 2^-33

#define P1S_PITCH 25216                     // 197 rows x 128 (row 196 = zeros)

typedef __attribute__((address_space(3))) u32 lds_u32;
typedef const __attribute__((address_space(1))) u32 glb_u32;
#define GLOAD16(G, L) __builtin_amdgcn_global_load_lds((glb_u32*)(G), (lds_u32*)(L), 16, 0, 0)

// ---------------------------------------------------------------------------
// K1: conv1+bn1+IF(T=8, const input)+2x2 maxpool -> spike BYTES in k2's
// swizzled layout: p1s[tb][(pix*128+ci) ^ ((pix&7)<<4)] = 0/1.
// ---------------------------------------------------------------------------
__global__ __launch_bounds__(256) void k1_conv1_if_pool(
    const float* __restrict__ x, const float* __restrict__ w1,
    const float* __restrict__ g1, const float* __restrict__ b1,
    const float* __restrict__ m1, const float* __restrict__ v1,
    u8* __restrict__ p1s)
{
    int bx = blockIdx.x;          // 512 = b*4 + cg
    int b = bx >> 2, cg = bx & 3;
    int tid = threadIdx.x;

    __shared__ float xs[NPIX1];
    __shared__ double wt[32][13];
    __shared__ u8 sbits[NPIX1 * 32];

    for (int i = tid; i < NPIX1; i += 256) xs[i] = x[(size_t)b * NPIX1 + i];
    if (tid < 32) {
        int co = cg * 32 + tid;
#pragma unroll
        for (int k = 0; k < 9; ++k) wt[tid][k] = (double)w1[co * 9 + k];
        double inv = (double)g1[co] / sqrt((double)v1[co] + 1e-5);
        wt[tid][9]  = inv;
        wt[tid][10] = (double)b1[co] - (double)m1[co] * inv;
    }
    __syncthreads();

    for (int i = tid; i < NPIX1 * 32; i += 256) {
        int co = i & 31, p = i >> 5;
        int y = p / 28, xx = p - y * 28;
        double acc = 0.0;
#pragma unroll
        for (int dy = 0; dy < 3; ++dy) {
            int iy = y + dy - 1;
#pragma unroll
            for (int dx = 0; dx < 3; ++dx) {
                int ix = xx + dx - 1;
                if (iy >= 0 && iy < 28 && ix >= 0 && ix < 28)
                    acc += (double)xs[iy * 28 + ix] * wt[co][dy * 3 + dx];
            }
        }
        double yv = acc * wt[co][9] + wt[co][10];
        double v = 0.0; u32 byte = 0;
#pragma unroll
        for (int t = 0; t < 8; ++t) {
            double h = v + yv;
            int s = (h >= 1.0);
            byte |= (u32)s << t;
            v = s ? 0.0 : h;
        }
        sbits[p * 32 + co] = (u8)byte;
    }
    __syncthreads();

    for (int i = tid; i < NPIX2 * 32; i += 256) {
        int co = i & 31, p14 = i >> 5;
        int y14 = p14 / 14, x14 = p14 - y14 * 14;
        int p0 = (2 * y14) * 28 + 2 * x14;
        u8 pv = sbits[p0 * 32 + co] | sbits[(p0 + 1) * 32 + co]
              | sbits[(p0 + 28) * 32 + co] | sbits[(p0 + 29) * 32 + co];
        int off = (p14 * 128 + cg * 32 + co) ^ ((p14 & 7) << 4);
#pragma unroll
        for (int t = 0; t < 8; ++t)
            p1s[(size_t)(t * BATCH + b) * P1S_PITCH + off] = (u8)((pv >> t) & 1);
    }
}

// ---------------------------------------------------------------------------
// K2w: quantize conv2 weights to 4 signed base-256 digits at scale 2^32.
// Fragment-order: Bt[(((d*9+tap)*4+ks)*4+Nt)*1024 + l*16 + bp]
// ---------------------------------------------------------------------------
__global__ __launch_bounds__(256) void k2w_quant(
    const float* __restrict__ w2, s8* __restrict__ Bt)
{
    int g = blockIdx.x * 256 + threadIdx.x;   // co*128+ci
    if (g >= CH * CH) return;
    int co = g >> 7, ci = g & 127;
    int ks = ci >> 5, rem = ci & 31, half = rem >> 4, bp = rem & 15;
    int l = (co & 31) | (half << 5);
    int Nt = co >> 5;
#pragma unroll
    for (int k = 0; k < 9; ++k) {
        double wd = (double)w2[(size_t)g * 9 + k] * W2_SCALE;
        long r = (long)llrint(wd);
#pragma unroll
        for (int d = 0; d < W2_DIGITS; ++d) {
            int dg = (int)(((r + 128) & 255) - 128);
            r = (r - (long)dg) >> 8;
            Bt[((size_t)(((d * 9 + k) * 4 + ks) * 4 + Nt)) * 1024 + l * 16 + bp] = (s8)dg;
        }
    }
}

// ---------------------------------------------------------------------------
// K2: FUSED conv2+bn2+IF2+pool, TWO timesteps per phase (B t-invariant ->
// every B LDS read feeds 2 MFMAs; reads/MFMA 1.25 -> 0.75). 512 thr = 8 waves,
// one M-tile per wave (geometry shared by both t -> one comb[9]).
// acc[2][4] (128 AGPR) + vst[16] + comb[9] ~ 205 regs < 256 cap of (512,2).
// LDS: sp[2] 49KB + bbuf dbuf 72KB + sbuf[2] 12.5KB = 133.5KB (1 blk/CU,
// 2 waves/SIMD as r13). ks-major, full B slab dbuf, 1 barrier/ks.
// IF order preserved: t0 epilogue then t1 on the same vst.
// ---------------------------------------------------------------------------
__global__ __launch_bounds__(512, 2) void k2_conv2_if_pool(
    const u8* __restrict__ p1s, const s8* __restrict__ Bt,
    const float* __restrict__ g2, const float* __restrict__ bb2,
    const float* __restrict__ m2, const float* __restrict__ v2,
    u8* __restrict__ z2)
{
    int bx = blockIdx.x;          // 512 = b*4 + cq
    int b = bx >> 2, cq = bx & 3;

    int tid = threadIdx.x;
    int lane = tid & 63;
    int lane32 = lane & 31;
    int khalf = (lane >> 5) << 4;
    int w = __builtin_amdgcn_readfirstlane(tid >> 6);  // wave 0..7 = M tile
    int rhi = (lane >> 5) * 4;

    __shared__ u8 sp[2][P1S_PITCH];     // two spike planes (t-pair)
    __shared__ u8 bbuf[2][36864];       // B slab dbuf: 9 taps x 4 digits
    __shared__ u8 sbuf[2][NPIX2 * 32];  // spike bytes for pooling (t-pair)

    // zero the dummy row 196 of both planes (never rewritten)
    if (tid < 16) {
        int pl = tid >> 3;
        *(uint4*)(sp[pl] + 196 * 128 + (tid & 7) * 16) = make_uint4(0u, 0u, 0u, 0u);
    }

    // bn2 constants (co = cq*32 + lane32)
    int co = cq * 32 + lane32;
    double binv  = (double)g2[co] / sqrt((double)v2[co] + 1e-5);
    double bbeta = (double)bb2[co] - (double)m2[co] * binv;

    // packed per-lane tap addresses (shared by both t); 196 = zero row
    int p = w * 32 + lane32;
    int valid = (p < NPIX2);
    int pe = valid ? p : 0;
    int py = pe / 14, px = pe - py * 14;
    int comb[9];
#pragma unroll
    for (int tap = 0; tap < 9; ++tap) {
        int dy = tap / 3 - 1, dx = tap - (tap / 3) * 3 - 1;
        int ny = py + dy, nx = px + dx;
        int ok = valid & (ny >= 0) & (ny < 14) & (nx >= 0) & (nx < 14);
        int pixn = ok ? (ny * 14 + nx) : 196;
        comb[tap] = pixn * 128 + ((pixn & 7) << 4);
    }

    // stage full B slab for k-slice ks -> bbuf[bufsel]: 36 frags over 8 waves
    auto stageB = [&](int ks, int bufsel) {
#pragma unroll
        for (int i = 0; i < 5; ++i) {
            int f = w + i * 8;        // 0..39, f = d*9+tap composite
            if (f < 36) {
                GLOAD16(Bt + ((size_t)((f * 4 + ks) * 4 + cq)) * 1024 + lane * 16,
                        bbuf[bufsel] + f * 1024);
            }
        }
    };

    // prologue: t=0,1 spike planes + slab ks=0 -> buf 0
    {
        const u8* s0 = p1s + (size_t)b * P1S_PITCH;
        const u8* s1 = p1s + (size_t)(BATCH + b) * P1S_PITCH;
        for (int i = tid; i < 1568; i += 512) GLOAD16(s0 + i * 16, sp[0] + i * 16);
        for (int i = tid; i < 1568; i += 512) GLOAD16(s1 + i * 16, sp[1] + i * 16);
        stageB(0, 0);
    }
    __syncthreads();

    double vst[16];
#pragma unroll
    for (int r = 0; r < 16; ++r) vst[r] = 0.0;

#pragma unroll 1
    for (int tg = 0; tg < 4; ++tg) {
        v16i acc[2][4];
#pragma unroll
        for (int h = 0; h < 2; ++h)
#pragma unroll
            for (int d = 0; d < 4; ++d)
#pragma unroll
                for (int r = 0; r < 16; ++r) acc[h][d][r] = 0;

#pragma unroll 1
        for (int ks = 0; ks < 4; ++ks) {
            int cur = ks & 1;
            // prefetch next slab (periodic mod 4; final prefetch harmless)
            stageB((ks + 1) & 3, cur ^ 1);

            int K = ks * 32 + khalf;
            const u8* bbp = bbuf[cur];
#pragma unroll
            for (int tap = 0; tap < 9; ++tap) {
                v4i A0 = *(const v4i*)(sp[0] + (comb[tap] ^ K));
                v4i A1 = *(const v4i*)(sp[1] + (comb[tap] ^ K));
#pragma unroll
                for (int d = 0; d < 4; ++d) {
                    v4i B = *(const v4i*)(bbp + (d * 9 + tap) * 1024 + lane * 16);
                    acc[0][d] = __builtin_amdgcn_mfma_i32_32x32x32_i8(A0, B, acc[0][d], 0, 0, 0);
                    acc[1][d] = __builtin_amdgcn_mfma_i32_32x32x32_i8(A1, B, acc[1][d], 0, 0, 0);
                }
            }
            __syncthreads();   // protects bbuf reuse + drains prefetch
        }

        // sp reads done for this pair; stage next pair's spike planes
        if (tg + 1 < 4) {
            const u8* sn0 = p1s + (size_t)((2 * tg + 2) * BATCH + b) * P1S_PITCH;
            const u8* sn1 = p1s + (size_t)((2 * tg + 3) * BATCH + b) * P1S_PITCH;
            for (int i = tid; i < 1568; i += 512) GLOAD16(sn0 + i * 16, sp[0] + i * 16);
            for (int i = tid; i < 1568; i += 512) GLOAD16(sn1 + i * 16, sp[1] + i * 16);
        }

        // merge digits (exact i64) + bn2 + IF steps: t0 then t1 on same vst
#pragma unroll
        for (int h = 0; h < 2; ++h) {
#pragma unroll
            for (int r = 0; r < 16; ++r) {
                long carry = ((long)acc[h][3][r] << 24) + ((long)acc[h][2][r] << 16)
                           + ((long)acc[h][1][r] << 8) + (long)acc[h][0][r];
                int pix = w * 32 + (r & 3) + 8 * (r >> 2) + rhi;
                double hin = (double)carry * W2_INVSCALE * binv + bbeta;
                double hv = vst[r] + hin;
                int s = (hv >= 1.0);
                vst[r] = s ? 0.0 : hv;
                if (pix < NPIX2) sbuf[h][pix * 32 + lane32] = (u8)s;
            }
        }
        __syncthreads();

        // 2x2 pool for both t -> z2[kb][tb][32]
        for (int j = tid; j < 2 * 49 * 32; j += 512) {
            int h = (j >= 49 * 32);
            int jj = j - h * (49 * 32);
            int w49 = jj >> 5, c32 = jj & 31;
            int wy = w49 / 7, wx = w49 - wy * 7;
            int p0 = (2 * wy) * 14 + 2 * wx;
            u8 s = sbuf[h][p0 * 32 + c32] | sbuf[h][(p0 + 1) * 32 + c32]
                 | sbuf[h][(p0 + 14) * 32 + c32] | sbuf[h][(p0 + 15) * 32 + c32];
            int i2 = (cq * 32 + c32) * 49 + w49;
            int tb = (2 * tg + h) * BATCH + b;
            z2[((size_t)(i2 >> 5) * TB + tb) * 32 + (i2 & 31)] = s;
        }
        __syncthreads();   // drains sp staging before next pair's A reads
    }
}

// ---------------------------------------------------------------------------
// K4w: quantize fc1 weights to 4 signed base-256 digits at scale 2^33.
// Layout Wd1[d][kb][o][32] i8.
// ---------------------------------------------------------------------------
__global__ __launch_bounds__(256) void k4w_quant(
    const float* __restrict__ fw, s8* __restrict__ Wd1)
{
    int g = blockIdx.x * 256 + threadIdx.x;   // kb*2048 + o
    if (g >= FC1_KB * FC1_OUT) return;
    int o = g & 2047, kb = g >> 11;

    u32 tmp[FC1_DIGITS][8];
#pragma unroll
    for (int d = 0; d < FC1_DIGITS; ++d)
#pragma unroll
        for (int q = 0; q < 8; ++q) tmp[d][q] = 0;

#pragma unroll
    for (int j = 0; j < 32; ++j) {
        double wd = (double)fw[(size_t)o * FC1_IN + kb * 32 + j] * FC1_SCALE;
        long r = (long)llrint(wd);
#pragma unroll
        for (int d = 0; d < FC1_DIGITS; ++d) {
            int dg = (int)(((r + 128) & 255) - 128);
            r = (r - (long)dg) >> 8;
            tmp[d][j >> 2] |= (u32)(dg & 255) << ((j & 3) * 8);
        }
    }
#pragma unroll
    for (int d = 0; d < FC1_DIGITS; ++d) {
        u32* dst = (u32*)(Wd1 + (((size_t)d * FC1_KB + kb) * FC1_OUT + o) * 32);
        *(uint4*)dst       = make_uint4(tmp[d][0], tmp[d][1], tmp[d][2], tmp[d][3]);
        *(uint4*)(dst + 4) = make_uint4(tmp[d][4], tmp[d][5], tmp[d][6], tmp[d][7]);
    }
}

// ---------------------------------------------------------------------------
// K4: fc1 via i8 MFMA, digit-split -> i32 partials. Grid 256 = mt8 x (nt8 x d4),
// bx = mt*32 + ntd so bx%8 = ntd%8 (same-B blocks colocate per XCD).
// Block 512 thr = 8 waves (2wm x 4wn), tile 128tb x 256o, wave 64x64 (2x2 sub).
// 98 phases x 2kb, 48KB LDS dbuf. Staging source is fragment-order.
// ---------------------------------------------------------------------------
__global__ __launch_bounds__(512, 2) void k4_fc1_i8(
    const u8* __restrict__ z2, const s8* __restrict__ Wd1,
    int* __restrict__ Hpart)
{
    __shared__ u8 stg[2 * 24576];   // [buf][A 8KB | B 16KB]

    int bx = blockIdx.x;
    int ntd = bx & 31, mt = bx >> 5;
    int nt = ntd >> 2, d = ntd & 3;

    int tid = threadIdx.x;
    int lane = tid & 63, lane32 = lane & 31;
    int half16 = (lane >> 5) << 4;
    int wv = __builtin_amdgcn_readfirstlane(tid >> 6);  // 0..7
    int wm = wv >> 2, wn = wv & 3;

    int tb0 = mt * 128, o0 = nt * 256;

    v16i acc00, acc01, acc10, acc11;
#pragma unroll
    for (int r = 0; r < 16; ++r) { acc00[r] = 0; acc01[r] = 0; acc10[r] = 0; acc11[r] = 0; }

    auto stage = [&](int q, int buf) {
        int kbg0 = q * 2;
        for (int i = wv; i < 24; i += 8) {
            if (i < 8) {
                int kbr = i >> 2, sub = i & 3;
                GLOAD16(z2 + ((size_t)(kbg0 + kbr) * TB + tb0 + sub * 32 + lane32) * 32 + half16,
                        stg + buf * 24576 + i * 1024);
            } else {
                int j = i - 8;
                int kbr = j >> 3, osub = j & 7;
                GLOAD16(Wd1 + (((size_t)d * FC1_KB + kbg0 + kbr) * FC1_OUT + o0 + osub * 32 + lane32) * 32 + half16,
                        stg + buf * 24576 + 8192 + j * 1024);
            }
        }
    };

    stage(0, 0);
    __syncthreads();

#pragma unroll 1
    for (int q = 0; q < 98; ++q) {
        int buf = q & 1;
        if (q + 1 < 98) stage(q + 1, buf ^ 1);
        const u8* A_ = stg + buf * 24576;
        const u8* B_ = A_ + 8192;
#pragma unroll
        for (int kbr = 0; kbr < 2; ++kbr) {
            v4i A0 = *(const v4i*)(A_ + (kbr * 4 + wm * 2 + 0) * 1024 + lane * 16);
            v4i A1 = *(const v4i*)(A_ + (kbr * 4 + wm * 2 + 1) * 1024 + lane * 16);
            v4i B0 = *(const v4i*)(B_ + (kbr * 8 + wn * 2 + 0) * 1024 + lane * 16);
            v4i B1 = *(const v4i*)(B_ + (kbr * 8 + wn * 2 + 1) * 1024 + lane * 16);
            acc00 = __builtin_amdgcn_mfma_i32_32x32x32_i8(A0, B0, acc00, 0, 0, 0);
            acc01 = __builtin_amdgcn_mfma_i32_32x32x32_i8(A0, B1, acc01, 0, 0, 0);
            acc10 = __builtin_amdgcn_mfma_i32_32x32x32_i8(A1, B0, acc10, 0, 0, 0);
            acc11 = __builtin_amdgcn_mfma_i32_32x32x32_i8(A1, B1, acc11, 0, 0, 0);
        }
        __syncthreads();
    }

    int rhi = (lane >> 5) << 2;
    int* Hd = Hpart + (size_t)d * TB * FC1_OUT;
#pragma unroll
    for (int r = 0; r < 16; ++r) {
        int row = (r & 3) + 8 * (r >> 2) + rhi;
        size_t b0 = (size_t)(tb0 + wm * 64 + row) * FC1_OUT + o0 + wn * 64 + lane32;
        Hd[b0]                             = acc00[r];
        Hd[b0 + 32]                        = acc01[r];
        Hd[b0 + (size_t)32 * FC1_OUT]      = acc10[r];
        Hd[b0 + (size_t)32 * FC1_OUT + 32] = acc11[r];
    }
}

// ---------------------------------------------------------------------------
// K5: combine digit partials (exact, c < 2^44) + IF over T -> s3
// ---------------------------------------------------------------------------
__global__ __launch_bounds__(256) void k5_if3(
    const int* __restrict__ Hpart, u8* __restrict__ s3)
{
    int g = blockIdx.x * 256 + threadIdx.x;   // 128*2048
    int b = g >> 11;
    int o = g & 2047;
    double v = 0.0;
#pragma unroll
    for (int t = 0; t < 8; ++t) {
        size_t idx = (size_t)(t * BATCH + b) * FC1_OUT + o;
        long c = 0;
#pragma unroll
        for (int d = 0; d < FC1_DIGITS; ++d)
            c += ((long)Hpart[(size_t)d * TB * FC1_OUT + idx]) << (8 * d);
        double h = v + (double)c * FC1_INVSCALE;
        int s = (h >= 1.0);
        v = s ? 0.0 : h;
        s3[idx] = (u8)s;
    }
}

// ---------------------------------------------------------------------------
// K6: fc2 h4[tb][16] = sum_i s3[tb][i]*fw2[o][i], f64. 256 thr, K-quarters.
// ---------------------------------------------------------------------------
__global__ __launch_bounds__(256) void k6_fc2(
    const u8* __restrict__ s3, const float* __restrict__ fw2,
    double* __restrict__ h4)
{
    int tb = blockIdx.x;
    int tid = threadIdx.x;
    int w = tid >> 6, lane = tid & 63;
    __shared__ double red[4][16];

    double acc[10];
#pragma unroll
    for (int o = 0; o < 10; ++o) acc[o] = 0.0;

#pragma unroll
    for (int it = 0; it < 8; ++it) {
        int i = w * 512 + it * 64 + lane;
        double zd = (double)s3[(size_t)tb * FC1_OUT + i];
#pragma unroll
        for (int o = 0; o < 10; ++o)
            acc[o] += zd * (double)fw2[o * FC1_OUT + i];
    }
#pragma unroll
    for (int o = 0; o < 10; ++o) {
#pragma unroll
        for (int off = 32; off >= 1; off >>= 1)
            acc[o] += __shfl_down(acc[o], off);
    }
    if (lane == 0) {
#pragma unroll
        for (int o = 0; o < 10; ++o) red[w][o] = acc[o];
    }
    __syncthreads();
    if (tid < 10)
        h4[(size_t)tb * 16 + tid] = red[0][tid] + red[1][tid] + red[2][tid] + red[3][tid];
}

// ---------------------------------------------------------------------------
// K7: IF over T on h4 + mean -> out[b][10] f32
// ---------------------------------------------------------------------------
__global__ __launch_bounds__(256) void k7_if4_mean(
    const double* __restrict__ h4, float* __restrict__ out)
{
    int g = blockIdx.x * 256 + threadIdx.x;
    if (g >= BATCH * FC2_OUT) return;
    int b = g / 10;
    int o = g - b * 10;
    double v = 0.0; int cnt = 0;
#pragma unroll
    for (int t = 0; t < 8; ++t) {
        double h = v + h4[(size_t)(t * BATCH + b) * 16 + o];
        int s = (h >= 1.0);
        cnt += s;
        v = s ? 0.0 : h;
    }
    out[b * 10 + o] = (float)cnt * 0.125f;
}

// ---------------------------------------------------------------------------
extern "C" void kernel_launch(void* const* d_in, const int* in_sizes, int n_in,
                              void* d_out, int out_size, void* d_ws, size_t ws_size,
                              hipStream_t stream)
{
    const float* x   = (const float*)d_in[0];
    const float* w1  = (const float*)d_in[1];
    const float* g1  = (const float*)d_in[2];
    const float* b1  = (const float*)d_in[3];
    const float* m1  = (const float*)d_in[4];
    const float* v1  = (const float*)d_in[5];
    const float* w2  = (const float*)d_in[6];
    const float* g2  = (const float*)d_in[7];
    const float* b2  = (const float*)d_in[8];
    const float* m2  = (const float*)d_in[9];
    const float* v2  = (const float*)d_in[10];
    const float* fw1 = (const float*)d_in[11];
    const float* fw2 = (const float*)d_in[12];
    float* out = (float*)d_out;

    char* ws = (char*)d_ws;
    size_t off = 0;
    auto alloc = [&](size_t sz) { size_t o = off; off = (off + sz + 255) & ~(size_t)255; return o; };

    size_t o_p1 = alloc((size_t)TB * P1S_PITCH);                         // 25.8 MB
    size_t o_z  = alloc((size_t)TB * FC1_IN);                            // 6.4 MB
    size_t o_s3 = alloc((size_t)TB * FC1_OUT);                           // 2.1 MB
    size_t o_h4 = alloc((size_t)TB * 16 * 8);                            // 128 KB
    size_t o_wd = alloc((size_t)W2_DIGITS * 9 * CH * CH);                // 590 KB
    size_t o_w1 = alloc((size_t)FC1_DIGITS * FC1_KB * FC1_OUT * 32);     // 51.4 MB
    size_t o_hp = alloc((size_t)FC1_DIGITS * TB * FC1_OUT * 4);          // 33.6 MB
    (void)ws_size;

    u8*     p1s    = (u8*)(ws + o_p1);
    u8*     z2     = (u8*)(ws + o_z);
    u8*     s3     = (u8*)(ws + o_s3);
    double* h4     = (double*)(ws + o_h4);
    s8*     Bt     = (s8*)(ws + o_wd);
    s8*     Wd1    = (s8*)(ws + o_w1);
    int*    Hpart  = (int*)(ws + o_hp);

    k2w_quant<<<dim3((CH * CH + 255) / 256), dim3(256), 0, stream>>>(w2, Bt);

    k4w_quant<<<dim3((FC1_KB * FC1_OUT + 255) / 256), dim3(256), 0, stream>>>(
        fw1, Wd1);

    k1_conv1_if_pool<<<dim3(512), dim3(256), 0, stream>>>(
        x, w1, g1, b1, m1, v1, p1s);

    k2_conv2_if_pool<<<dim3(512), dim3(512), 0, stream>>>(
        p1s, Bt, g2, b2, m2, v2, z2);

    k4_fc1_i8<<<dim3(256), dim3(512), 0, stream>>>(z2, Wd1, Hpart);

    k5_if3<<<dim3(BATCH * FC1_OUT / 256), dim3(256), 0, stream>>>(Hpart, s3);

    k6_fc2<<<dim3(TB), dim3(256), 0, stream>>>(s3, fw2, h4);

    k7_if4_mean<<<dim3((BATCH * FC2_OUT + 255) / 256), dim3(256), 0, stream>>>(h4, out);
}

// Round 18
// 312.504 us; speedup vs baseline: 1.2174x; 1.0405x over previous
//
#include <hip/hip_runtime.h>
#include <stdint.h>

typedef unsigned int u32;
typedef unsigned long long u64;
typedef unsigned char u8;
typedef signed char s8;
typedef int v4i __attribute__((ext_vector_type(4)));
typedef int v16i __attribute__((ext_vector_type(16)));

#define TSTEPS 8
#define BATCH 128
#define CH 128
#define NPIX1 784   // 28*28
#define NPIX2 196   // 14*14
#define TB 1024     // TSTEPS*BATCH
#define FC1_OUT 2048
#define FC1_IN 6272 // 128*49
#define FC2_OUT 10

// conv2: 4 signed base-256 digits, scale 2^32
#define W2_DIGITS 4
#define W2_SCALE 4294967296.0               // 2^32
#define W2_INVSCALE 2.3283064365386963e-10  // 2^-32

// fc1: 4 signed base-256 digits, scale 2^33
#define FC1_DIGITS 4
#define FC1_KB 196                          // 6272/32
#define FC1_SCALE 8589934592.0              // 2^33
#define FC1_INVSCALE 1.1641532182693481e-10 // 2^-33

#define P1S_PITCH 25216                     // 197 rows x 128 (row 196 = zeros)

typedef __attribute__((address_space(3))) u32 lds_u32;
typedef const __attribute__((address_space(1))) u32 glb_u32;
#define GLOAD16(G, L) __builtin_amdgcn_global_load_lds((glb_u32*)(G), (lds_u32*)(L), 16, 0, 0)

// ---------------------------------------------------------------------------
// K1: conv1+bn1+IF(T=8, const input)+2x2 maxpool -> spike BYTES in k2's
// swizzled layout: p1s[tb][(pix*128+ci) ^ ((pix&7)<<4)] = 0/1.
// Final store loop vectorized: 4 channels/thread, one u32 store per t
// (XOR swizzle touches bits 4-6 only, so 4-byte groups stay contiguous).
// ---------------------------------------------------------------------------
__global__ __launch_bounds__(256) void k1_conv1_if_pool(
    const float* __restrict__ x, const float* __restrict__ w1,
    const float* __restrict__ g1, const float* __restrict__ b1,
    const float* __restrict__ m1, const float* __restrict__ v1,
    u8* __restrict__ p1s)
{
    int bx = blockIdx.x;          // 512 = b*4 + cg
    int b = bx >> 2, cg = bx & 3;
    int tid = threadIdx.x;

    __shared__ float xs[NPIX1];
    __shared__ double wt[32][13];
    __shared__ u8 sbits[NPIX1 * 32];

    for (int i = tid; i < NPIX1; i += 256) xs[i] = x[(size_t)b * NPIX1 + i];
    if (tid < 32) {
        int co = cg * 32 + tid;
#pragma unroll
        for (int k = 0; k < 9; ++k) wt[tid][k] = (double)w1[co * 9 + k];
        double inv = (double)g1[co] / sqrt((double)v1[co] + 1e-5);
        wt[tid][9]  = inv;
        wt[tid][10] = (double)b1[co] - (double)m1[co] * inv;
    }
    __syncthreads();

    for (int i = tid; i < NPIX1 * 32; i += 256) {
        int co = i & 31, p = i >> 5;
        int y = p / 28, xx = p - y * 28;
        double acc = 0.0;
#pragma unroll
        for (int dy = 0; dy < 3; ++dy) {
            int iy = y + dy - 1;
#pragma unroll
            for (int dx = 0; dx < 3; ++dx) {
                int ix = xx + dx - 1;
                if (iy >= 0 && iy < 28 && ix >= 0 && ix < 28)
                    acc += (double)xs[iy * 28 + ix] * wt[co][dy * 3 + dx];
            }
        }
        double yv = acc * wt[co][9] + wt[co][10];
        double v = 0.0; u32 byte = 0;
#pragma unroll
        for (int t = 0; t < 8; ++t) {
            double h = v + yv;
            int s = (h >= 1.0);
            byte |= (u32)s << t;
            v = s ? 0.0 : h;
        }
        sbits[p * 32 + co] = (u8)byte;
    }
    __syncthreads();

    for (int i = tid; i < NPIX2 * 8; i += 256) {
        int c4 = i & 7, p14 = i >> 3;
        int y14 = p14 / 14, x14 = p14 - y14 * 14;
        int p0 = (2 * y14) * 28 + 2 * x14;
        u32 pv4 = *(const u32*)(sbits + p0 * 32 + c4 * 4)
                | *(const u32*)(sbits + (p0 + 1) * 32 + c4 * 4)
                | *(const u32*)(sbits + (p0 + 28) * 32 + c4 * 4)
                | *(const u32*)(sbits + (p0 + 29) * 32 + c4 * 4);
        int off = (p14 * 128 + cg * 32 + c4 * 4) ^ ((p14 & 7) << 4);
#pragma unroll
        for (int t = 0; t < 8; ++t) {
            u32 b4 = (pv4 >> t) & 0x01010101u;
            *(u32*)(p1s + (size_t)(t * BATCH + b) * P1S_PITCH + off) = b4;
        }
    }
}

// ---------------------------------------------------------------------------
// K2w: quantize conv2 weights to 4 signed base-256 digits at scale 2^32.
// Fragment-order: Bt[(((d*9+tap)*4+ks)*4+Nt)*1024 + l*16 + bp]
// ---------------------------------------------------------------------------
__global__ __launch_bounds__(256) void k2w_quant(
    const float* __restrict__ w2, s8* __restrict__ Bt)
{
    int g = blockIdx.x * 256 + threadIdx.x;   // co*128+ci
    if (g >= CH * CH) return;
    int co = g >> 7, ci = g & 127;
    int ks = ci >> 5, rem = ci & 31, half = rem >> 4, bp = rem & 15;
    int l = (co & 31) | (half << 5);
    int Nt = co >> 5;
#pragma unroll
    for (int k = 0; k < 9; ++k) {
        double wd = (double)w2[(size_t)g * 9 + k] * W2_SCALE;
        long r = (long)llrint(wd);
#pragma unroll
        for (int d = 0; d < W2_DIGITS; ++d) {
            int dg = (int)(((r + 128) & 255) - 128);
            r = (r - (long)dg) >> 8;
            Bt[((size_t)(((d * 9 + k) * 4 + ks) * 4 + Nt)) * 1024 + l * 16 + bp] = (s8)dg;
        }
    }
}

// ---------------------------------------------------------------------------
// K2: FUSED conv2+bn2+IF2+pool, TWO timesteps per phase (r17, 169us).
// Epilogue digit-merge in exact f64 Horner (|carry|<2^43 -> every step exact,
// bit-identical to the i64 path, fewer VALU ops). Pool reads sbuf as u32.
// ---------------------------------------------------------------------------
__global__ __launch_bounds__(512, 2) void k2_conv2_if_pool(
    const u8* __restrict__ p1s, const s8* __restrict__ Bt,
    const float* __restrict__ g2, const float* __restrict__ bb2,
    const float* __restrict__ m2, const float* __restrict__ v2,
    u8* __restrict__ z2)
{
    int bx = blockIdx.x;          // 512 = b*4 + cq
    int b = bx >> 2, cq = bx & 3;

    int tid = threadIdx.x;
    int lane = tid & 63;
    int lane32 = lane & 31;
    int khalf = (lane >> 5) << 4;
    int w = __builtin_amdgcn_readfirstlane(tid >> 6);  // wave 0..7 = M tile
    int rhi = (lane >> 5) * 4;

    __shared__ u8 sp[2][P1S_PITCH];     // two spike planes (t-pair)
    __shared__ u8 bbuf[2][36864];       // B slab dbuf: 9 taps x 4 digits
    __shared__ u8 sbuf[2][NPIX2 * 32];  // spike bytes for pooling (t-pair)

    // zero the dummy row 196 of both planes (never rewritten)
    if (tid < 16) {
        int pl = tid >> 3;
        *(uint4*)(sp[pl] + 196 * 128 + (tid & 7) * 16) = make_uint4(0u, 0u, 0u, 0u);
    }

    // bn2 constants (co = cq*32 + lane32)
    int co = cq * 32 + lane32;
    double binv  = (double)g2[co] / sqrt((double)v2[co] + 1e-5);
    double bbeta = (double)bb2[co] - (double)m2[co] * binv;

    // packed per-lane tap addresses (shared by both t); 196 = zero row
    int p = w * 32 + lane32;
    int valid = (p < NPIX2);
    int pe = valid ? p : 0;
    int py = pe / 14, px = pe - py * 14;
    int comb[9];
#pragma unroll
    for (int tap = 0; tap < 9; ++tap) {
        int dy = tap / 3 - 1, dx = tap - (tap / 3) * 3 - 1;
        int ny = py + dy, nx = px + dx;
        int ok = valid & (ny >= 0) & (ny < 14) & (nx >= 0) & (nx < 14);
        int pixn = ok ? (ny * 14 + nx) : 196;
        comb[tap] = pixn * 128 + ((pixn & 7) << 4);
    }

    // stage full B slab for k-slice ks -> bbuf[bufsel]: 36 frags over 8 waves
    auto stageB = [&](int ks, int bufsel) {
#pragma unroll
        for (int i = 0; i < 5; ++i) {
            int f = w + i * 8;        // 0..39, f = d*9+tap composite
            if (f < 36) {
                GLOAD16(Bt + ((size_t)((f * 4 + ks) * 4 + cq)) * 1024 + lane * 16,
                        bbuf[bufsel] + f * 1024);
            }
        }
    };

    // prologue: t=0,1 spike planes + slab ks=0 -> buf 0
    {
        const u8* s0 = p1s + (size_t)b * P1S_PITCH;
        const u8* s1 = p1s + (size_t)(BATCH + b) * P1S_PITCH;
        for (int i = tid; i < 1568; i += 512) GLOAD16(s0 + i * 16, sp[0] + i * 16);
        for (int i = tid; i < 1568; i += 512) GLOAD16(s1 + i * 16, sp[1] + i * 16);
        stageB(0, 0);
    }
    __syncthreads();

    double vst[16];
#pragma unroll
    for (int r = 0; r < 16; ++r) vst[r] = 0.0;

#pragma unroll 1
    for (int tg = 0; tg < 4; ++tg) {
        v16i acc[2][4];
#pragma unroll
        for (int h = 0; h < 2; ++h)
#pragma unroll
            for (int d = 0; d < 4; ++d)
#pragma unroll
                for (int r = 0; r < 16; ++r) acc[h][d][r] = 0;

#pragma unroll 1
        for (int ks = 0; ks < 4; ++ks) {
            int cur = ks & 1;
            // prefetch next slab (periodic mod 4; final prefetch harmless)
            stageB((ks + 1) & 3, cur ^ 1);

            int K = ks * 32 + khalf;
            const u8* bbp = bbuf[cur];
#pragma unroll
            for (int tap = 0; tap < 9; ++tap) {
                v4i A0 = *(const v4i*)(sp[0] + (comb[tap] ^ K));
                v4i A1 = *(const v4i*)(sp[1] + (comb[tap] ^ K));
#pragma unroll
                for (int d = 0; d < 4; ++d) {
                    v4i B = *(const v4i*)(bbp + (d * 9 + tap) * 1024 + lane * 16);
                    acc[0][d] = __builtin_amdgcn_mfma_i32_32x32x32_i8(A0, B, acc[0][d], 0, 0, 0);
                    acc[1][d] = __builtin_amdgcn_mfma_i32_32x32x32_i8(A1, B, acc[1][d], 0, 0, 0);
                }
            }
            __syncthreads();   // protects bbuf reuse + drains prefetch
        }

        // sp reads done for this pair; stage next pair's spike planes
        if (tg + 1 < 4) {
            const u8* sn0 = p1s + (size_t)((2 * tg + 2) * BATCH + b) * P1S_PITCH;
            const u8* sn1 = p1s + (size_t)((2 * tg + 3) * BATCH + b) * P1S_PITCH;
            for (int i = tid; i < 1568; i += 512) GLOAD16(sn0 + i * 16, sp[0] + i * 16);
            for (int i = tid; i < 1568; i += 512) GLOAD16(sn1 + i * 16, sp[1] + i * 16);
        }

        // merge digits (exact f64 Horner) + bn2 + IF steps: t0 then t1, same vst
#pragma unroll
        for (int h = 0; h < 2; ++h) {
#pragma unroll
            for (int r = 0; r < 16; ++r) {
                double carry = (((double)acc[h][3][r] * 256.0 + (double)acc[h][2][r]) * 256.0
                               + (double)acc[h][1][r]) * 256.0 + (double)acc[h][0][r];
                int pix = w * 32 + (r & 3) + 8 * (r >> 2) + rhi;
                double hin = carry * W2_INVSCALE * binv + bbeta;
                double hv = vst[r] + hin;
                int s = (hv >= 1.0);
                vst[r] = s ? 0.0 : hv;
                if (pix < NPIX2) sbuf[h][pix * 32 + lane32] = (u8)s;
            }
        }
        __syncthreads();

        // 2x2 pool for both t -> z2[kb][tb][32] (u32 sbuf reads)
        for (int j = tid; j < 2 * 49 * 8; j += 512) {
            int h = (j >= 49 * 8);
            int jj = j - h * (49 * 8);
            int w49 = jj >> 3, c4 = jj & 7;
            int wy = w49 / 7, wx = w49 - wy * 7;
            int p0 = (2 * wy) * 14 + 2 * wx;
            u32 s4 = *(const u32*)(sbuf[h] + p0 * 32 + c4 * 4)
                   | *(const u32*)(sbuf[h] + (p0 + 1) * 32 + c4 * 4)
                   | *(const u32*)(sbuf[h] + (p0 + 14) * 32 + c4 * 4)
                   | *(const u32*)(sbuf[h] + (p0 + 15) * 32 + c4 * 4);
            int tb = (2 * tg + h) * BATCH + b;
#pragma unroll
            for (int e = 0; e < 4; ++e) {
                int c32 = c4 * 4 + e;
                int i2 = (cq * 32 + c32) * 49 + w49;
                z2[((size_t)(i2 >> 5) * TB + tb) * 32 + (i2 & 31)] = (u8)((s4 >> (8 * e)) & 1u);
            }
        }
        __syncthreads();   // drains sp staging before next pair's A reads
    }
}

// ---------------------------------------------------------------------------
// K4w: quantize fc1 weights to 4 signed base-256 digits at scale 2^33.
// Layout Wd1[d][kb][o][32] i8.
// ---------------------------------------------------------------------------
__global__ __launch_bounds__(256) void k4w_quant(
    const float* __restrict__ fw, s8* __restrict__ Wd1)
{
    int g = blockIdx.x * 256 + threadIdx.x;   // kb*2048 + o
    if (g >= FC1_KB * FC1_OUT) return;
    int o = g & 2047, kb = g >> 11;

    u32 tmp[FC1_DIGITS][8];
#pragma unroll
    for (int d = 0; d < FC1_DIGITS; ++d)
#pragma unroll
        for (int q = 0; q < 8; ++q) tmp[d][q] = 0;

#pragma unroll
    for (int j = 0; j < 32; ++j) {
        double wd = (double)fw[(size_t)o * FC1_IN + kb * 32 + j] * FC1_SCALE;
        long r = (long)llrint(wd);
#pragma unroll
        for (int d = 0; d < FC1_DIGITS; ++d) {
            int dg = (int)(((r + 128) & 255) - 128);
            r = (r - (long)dg) >> 8;
            tmp[d][j >> 2] |= (u32)(dg & 255) << ((j & 3) * 8);
        }
    }
#pragma unroll
    for (int d = 0; d < FC1_DIGITS; ++d) {
        u32* dst = (u32*)(Wd1 + (((size_t)d * FC1_KB + kb) * FC1_OUT + o) * 32);
        *(uint4*)dst       = make_uint4(tmp[d][0], tmp[d][1], tmp[d][2], tmp[d][3]);
        *(uint4*)(dst + 4) = make_uint4(tmp[d][4], tmp[d][5], tmp[d][6], tmp[d][7]);
    }
}

// ---------------------------------------------------------------------------
// K4: fc1 via i8 MFMA, digit-split -> i32 partials. Grid 256 = mt8 x (nt8 x d4),
// bx = mt*32 + ntd so bx%8 = ntd%8 (same-B blocks colocate per XCD).
// Block 512 thr = 8 waves (2wm x 4wn), tile 128tb x 256o, wave 64x64 (2x2 sub).
// 98 phases x 2kb, 48KB LDS dbuf. Staging source is fragment-order.
// ---------------------------------------------------------------------------
__global__ __launch_bounds__(512, 2) void k4_fc1_i8(
    const u8* __restrict__ z2, const s8* __restrict__ Wd1,
    int* __restrict__ Hpart)
{
    __shared__ u8 stg[2 * 24576];   // [buf][A 8KB | B 16KB]

    int bx = blockIdx.x;
    int ntd = bx & 31, mt = bx >> 5;
    int nt = ntd >> 2, d = ntd & 3;

    int tid = threadIdx.x;
    int lane = tid & 63, lane32 = lane & 31;
    int half16 = (lane >> 5) << 4;
    int wv = __builtin_amdgcn_readfirstlane(tid >> 6);  // 0..7
    int wm = wv >> 2, wn = wv & 3;

    int tb0 = mt * 128, o0 = nt * 256;

    v16i acc00, acc01, acc10, acc11;
#pragma unroll
    for (int r = 0; r < 16; ++r) { acc00[r] = 0; acc01[r] = 0; acc10[r] = 0; acc11[r] = 0; }

    auto stage = [&](int q, int buf) {
        int kbg0 = q * 2;
        for (int i = wv; i < 24; i += 8) {
            if (i < 8) {
                int kbr = i >> 2, sub = i & 3;
                GLOAD16(z2 + ((size_t)(kbg0 + kbr) * TB + tb0 + sub * 32 + lane32) * 32 + half16,
                        stg + buf * 24576 + i * 1024);
            } else {
                int j = i - 8;
                int kbr = j >> 3, osub = j & 7;
                GLOAD16(Wd1 + (((size_t)d * FC1_KB + kbg0 + kbr) * FC1_OUT + o0 + osub * 32 + lane32) * 32 + half16,
                        stg + buf * 24576 + 8192 + j * 1024);
            }
        }
    };

    stage(0, 0);
    __syncthreads();

#pragma unroll 1
    for (int q = 0; q < 98; ++q) {
        int buf = q & 1;
        if (q + 1 < 98) stage(q + 1, buf ^ 1);
        const u8* A_ = stg + buf * 24576;
        const u8* B_ = A_ + 8192;
#pragma unroll
        for (int kbr = 0; kbr < 2; ++kbr) {
            v4i A0 = *(const v4i*)(A_ + (kbr * 4 + wm * 2 + 0) * 1024 + lane * 16);
            v4i A1 = *(const v4i*)(A_ + (kbr * 4 + wm * 2 + 1) * 1024 + lane * 16);
            v4i B0 = *(const v4i*)(B_ + (kbr * 8 + wn * 2 + 0) * 1024 + lane * 16);
            v4i B1 = *(const v4i*)(B_ + (kbr * 8 + wn * 2 + 1) * 1024 + lane * 16);
            acc00 = __builtin_amdgcn_mfma_i32_32x32x32_i8(A0, B0, acc00, 0, 0, 0);
            acc01 = __builtin_amdgcn_mfma_i32_32x32x32_i8(A0, B1, acc01, 0, 0, 0);
            acc10 = __builtin_amdgcn_mfma_i32_32x32x32_i8(A1, B0, acc10, 0, 0, 0);
            acc11 = __builtin_amdgcn_mfma_i32_32x32x32_i8(A1, B1, acc11, 0, 0, 0);
        }
        __syncthreads();
    }

    int rhi = (lane >> 5) << 2;
    int* Hd = Hpart + (size_t)d * TB * FC1_OUT;
#pragma unroll
    for (int r = 0; r < 16; ++r) {
        int row = (r & 3) + 8 * (r >> 2) + rhi;
        size_t b0 = (size_t)(tb0 + wm * 64 + row) * FC1_OUT + o0 + wn * 64 + lane32;
        Hd[b0]                             = acc00[r];
        Hd[b0 + 32]                        = acc01[r];
        Hd[b0 + (size_t)32 * FC1_OUT]      = acc10[r];
        Hd[b0 + (size_t)32 * FC1_OUT + 32] = acc11[r];
    }
}

// ---------------------------------------------------------------------------
// K5: combine digit partials (exact, c < 2^44) + IF over T -> s3
// ---------------------------------------------------------------------------
__global__ __launch_bounds__(256) void k5_if3(
    const int* __restrict__ Hpart, u8* __restrict__ s3)
{
    int g = blockIdx.x * 256 + threadIdx.x;   // 128*2048
    int b = g >> 11;
    int o = g & 2047;
    double v = 0.0;
#pragma unroll
    for (int t = 0; t < 8; ++t) {
        size_t idx = (size_t)(t * BATCH + b) * FC1_OUT + o;
        long c = 0;
#pragma unroll
        for (int d = 0; d < FC1_DIGITS; ++d)
            c += ((long)Hpart[(size_t)d * TB * FC1_OUT + idx]) << (8 * d);
        double h = v + (double)c * FC1_INVSCALE;
        int s = (h >= 1.0);
        v = s ? 0.0 : h;
        s3[idx] = (u8)s;
    }
}

// ---------------------------------------------------------------------------
// K6: fc2 h4[tb][16] = sum_i s3[tb][i]*fw2[o][i], f64. 256 thr, K-quarters.
// ---------------------------------------------------------------------------
__global__ __launch_bounds__(256) void k6_fc2(
    const u8* __restrict__ s3, const float* __restrict__ fw2,
    double* __restrict__ h4)
{
    int tb = blockIdx.x;
    int tid = threadIdx.x;
    int w = tid >> 6, lane = tid & 63;
    __shared__ double red[4][16];

    double acc[10];
#pragma unroll
    for (int o = 0; o < 10; ++o) acc[o] = 0.0;

#pragma unroll
    for (int it = 0; it < 8; ++it) {
        int i = w * 512 + it * 64 + lane;
        double zd = (double)s3[(size_t)tb * FC1_OUT + i];
#pragma unroll
        for (int o = 0; o < 10; ++o)
            acc[o] += zd * (double)fw2[o * FC1_OUT + i];
    }
#pragma unroll
    for (int o = 0; o < 10; ++o) {
#pragma unroll
        for (int off = 32; off >= 1; off >>= 1)
            acc[o] += __shfl_down(acc[o], off);
    }
    if (lane == 0) {
#pragma unroll
        for (int o = 0; o < 10; ++o) red[w][o] = acc[o];
    }
    __syncthreads();
    if (tid < 10)
        h4[(size_t)tb * 16 + tid] = red[0][tid] + red[1][tid] + red[2][tid] + red[3][tid];
}

// ---------------------------------------------------------------------------
// K7: IF over T on h4 + mean -> out[b][10] f32
// ---------------------------------------------------------------------------
__global__ __launch_bounds__(256) void k7_if4_mean(
    const double* __restrict__ h4, float* __restrict__ out)
{
    int g = blockIdx.x * 256 + threadIdx.x;
    if (g >= BATCH * FC2_OUT) return;
    int b = g / 10;
    int o = g - b * 10;
    double v = 0.0; int cnt = 0;
#pragma unroll
    for (int t = 0; t < 8; ++t) {
        double h = v + h4[(size_t)(t * BATCH + b) * 16 + o];
        int s = (h >= 1.0);
        cnt += s;
        v = s ? 0.0 : h;
    }
    out[b * 10 + o] = (float)cnt * 0.125f;
}

// ---------------------------------------------------------------------------
extern "C" void kernel_launch(void* const* d_in, const int* in_sizes, int n_in,
                              void* d_out, int out_size, void* d_ws, size_t ws_size,
                              hipStream_t stream)
{
    const float* x   = (const float*)d_in[0];
    const float* w1  = (const float*)d_in[1];
    const float* g1  = (const float*)d_in[2];
    const float* b1  = (const float*)d_in[3];
    const float* m1  = (const float*)d_in[4];
    const float* v1  = (const float*)d_in[5];
    const float* w2  = (const float*)d_in[6];
    const float* g2  = (const float*)d_in[7];
    const float* b2  = (const float*)d_in[8];
    const float* m2  = (const float*)d_in[9];
    const float* v2  = (const float*)d_in[10];
    const float* fw1 = (const float*)d_in[11];
    const float* fw2 = (const float*)d_in[12];
    float* out = (float*)d_out;

    char* ws = (char*)d_ws;
    size_t off = 0;
    auto alloc = [&](size_t sz) { size_t o = off; off = (off + sz + 255) & ~(size_t)255; return o; };

    size_t o_p1 = alloc((size_t)TB * P1S_PITCH);                         // 25.8 MB
    size_t o_z  = alloc((size_t)TB * FC1_IN);                            // 6.4 MB
    size_t o_s3 = alloc((size_t)TB * FC1_OUT);                           // 2.1 MB
    size_t o_h4 = alloc((size_t)TB * 16 * 8);                            // 128 KB
    size_t o_wd = alloc((size_t)W2_DIGITS * 9 * CH * CH);                // 590 KB
    size_t o_w1 = alloc((size_t)FC1_DIGITS * FC1_KB * FC1_OUT * 32);     // 51.4 MB
    size_t o_hp = alloc((size_t)FC1_DIGITS * TB * FC1_OUT * 4);          // 33.6 MB
    (void)ws_size;

    u8*     p1s    = (u8*)(ws + o_p1);
    u8*     z2     = (u8*)(ws + o_z);
    u8*     s3     = (u8*)(ws + o_s3);
    double* h4     = (double*)(ws + o_h4);
    s8*     Bt     = (s8*)(ws + o_wd);
    s8*     Wd1    = (s8*)(ws + o_w1);
    int*    Hpart  = (int*)(ws + o_hp);

    k2w_quant<<<dim3((CH * CH + 255) / 256), dim3(256), 0, stream>>>(w2, Bt);

    k4w_quant<<<dim3((FC1_KB * FC1_OUT + 255) / 256), dim3(256), 0, stream>>>(
        fw1, Wd1);

    k1_conv1_if_pool<<<dim3(512), dim3(256), 0, stream>>>(
        x, w1, g1, b1, m1, v1, p1s);

    k2_conv2_if_pool<<<dim3(512), dim3(512), 0, stream>>>(
        p1s, Bt, g2, b2, m2, v2, z2);

    k4_fc1_i8<<<dim3(256), dim3(512), 0, stream>>>(z2, Wd1, Hpart);

    k5_if3<<<dim3(BATCH * FC1_OUT / 256), dim3(256), 0, stream>>>(Hpart, s3);

    k6_fc2<<<dim3(TB), dim3(256), 0, stream>>>(s3, fw2, h4);

    k7_if4_mean<<<dim3((BATCH * FC2_OUT + 255) / 256), dim3(256), 0, stream>>>(h4, out);
}

// Round 19
// 301.200 us; speedup vs baseline: 1.2631x; 1.0375x over previous
//
#include <hip/hip_runtime.h>
#include <stdint.h>

typedef unsigned int u32;
typedef unsigned long long u64;
typedef unsigned char u8;
typedef signed char s8;
typedef int v4i __attribute__((ext_vector_type(4)));
typedef int v16i __attribute__((ext_vector_type(16)));

#define TSTEPS 8
#define BATCH 128
#define CH 128
#define NPIX1 784   // 28*28
#define NPIX2 196   // 14*14
#define TB 1024     // TSTEPS*BATCH
#define FC1_OUT 2048
#define FC1_IN 6272 // 128*49
#define FC2_OUT 10

// conv2: 4 signed base-256 digits, scale 2^32
#define W2_DIGITS 4
#define W2_SCALE 4294967296.0               // 2^32
#define W2_INVSCALE 2.3283064365386963e-10  // 2^-32

// fc1: 4 signed base-256 digits, scale 2^33
#define FC1_DIGITS 4
#define FC1_KB 196                          // 6272/32
#define FC1_SCALE 8589934592.0              // 2^33
#define FC1_INVSCALE 1.1641532182693481e-10 // 2^-33

#define P1S_PITCH 25216                     // 197 rows x 128 (row 196 = zeros)

typedef __attribute__((address_space(3))) u32 lds_u32;
typedef const __attribute__((address_space(1))) u32 glb_u32;
#define GLOAD16(G, L) __builtin_amdgcn_global_load_lds((glb_u32*)(G), (lds_u32*)(L), 16, 0, 0)

// ---------------------------------------------------------------------------
// K1: conv1+bn1+IF(T=8, const input)+2x2 maxpool -> spike BYTES in k2's
// swizzled layout: p1s[tb][(pix*128+ci) ^ ((pix&7)<<4)] = 0/1.
// Final store loop vectorized: 4 channels/thread, one u32 store per t.
// ---------------------------------------------------------------------------
__global__ __launch_bounds__(256) void k1_conv1_if_pool(
    const float* __restrict__ x, const float* __restrict__ w1,
    const float* __restrict__ g1, const float* __restrict__ b1,
    const float* __restrict__ m1, const float* __restrict__ v1,
    u8* __restrict__ p1s)
{
    int bx = blockIdx.x;          // 512 = b*4 + cg
    int b = bx >> 2, cg = bx & 3;
    int tid = threadIdx.x;

    __shared__ float xs[NPIX1];
    __shared__ double wt[32][13];
    __shared__ u8 sbits[NPIX1 * 32];

    for (int i = tid; i < NPIX1; i += 256) xs[i] = x[(size_t)b * NPIX1 + i];
    if (tid < 32) {
        int co = cg * 32 + tid;
#pragma unroll
        for (int k = 0; k < 9; ++k) wt[tid][k] = (double)w1[co * 9 + k];
        double inv = (double)g1[co] / sqrt((double)v1[co] + 1e-5);
        wt[tid][9]  = inv;
        wt[tid][10] = (double)b1[co] - (double)m1[co] * inv;
    }
    __syncthreads();

    for (int i = tid; i < NPIX1 * 32; i += 256) {
        int co = i & 31, p = i >> 5;
        int y = p / 28, xx = p - y * 28;
        double acc = 0.0;
#pragma unroll
        for (int dy = 0; dy < 3; ++dy) {
            int iy = y + dy - 1;
#pragma unroll
            for (int dx = 0; dx < 3; ++dx) {
                int ix = xx + dx - 1;
                if (iy >= 0 && iy < 28 && ix >= 0 && ix < 28)
                    acc += (double)xs[iy * 28 + ix] * wt[co][dy * 3 + dx];
            }
        }
        double yv = acc * wt[co][9] + wt[co][10];
        double v = 0.0; u32 byte = 0;
#pragma unroll
        for (int t = 0; t < 8; ++t) {
            double h = v + yv;
            int s = (h >= 1.0);
            byte |= (u32)s << t;
            v = s ? 0.0 : h;
        }
        sbits[p * 32 + co] = (u8)byte;
    }
    __syncthreads();

    for (int i = tid; i < NPIX2 * 8; i += 256) {
        int c4 = i & 7, p14 = i >> 3;
        int y14 = p14 / 14, x14 = p14 - y14 * 14;
        int p0 = (2 * y14) * 28 + 2 * x14;
        u32 pv4 = *(const u32*)(sbits + p0 * 32 + c4 * 4)
                | *(const u32*)(sbits + (p0 + 1) * 32 + c4 * 4)
                | *(const u32*)(sbits + (p0 + 28) * 32 + c4 * 4)
                | *(const u32*)(sbits + (p0 + 29) * 32 + c4 * 4);
        int off = (p14 * 128 + cg * 32 + c4 * 4) ^ ((p14 & 7) << 4);
#pragma unroll
        for (int t = 0; t < 8; ++t) {
            u32 b4 = (pv4 >> t) & 0x01010101u;
            *(u32*)(p1s + (size_t)(t * BATCH + b) * P1S_PITCH + off) = b4;
        }
    }
}

// ---------------------------------------------------------------------------
// K2w: quantize conv2 weights to 4 signed base-256 digits at scale 2^32.
// Fragment-order: Bt[(((d*9+tap)*4+ks)*4+Nt)*1024 + l*16 + bp]
// ---------------------------------------------------------------------------
__global__ __launch_bounds__(256) void k2w_quant(
    const float* __restrict__ w2, s8* __restrict__ Bt)
{
    int g = blockIdx.x * 256 + threadIdx.x;   // co*128+ci
    if (g >= CH * CH) return;
    int co = g >> 7, ci = g & 127;
    int ks = ci >> 5, rem = ci & 31, half = rem >> 4, bp = rem & 15;
    int l = (co & 31) | (half << 5);
    int Nt = co >> 5;
#pragma unroll
    for (int k = 0; k < 9; ++k) {
        double wd = (double)w2[(size_t)g * 9 + k] * W2_SCALE;
        long r = (long)llrint(wd);
#pragma unroll
        for (int d = 0; d < W2_DIGITS; ++d) {
            int dg = (int)(((r + 128) & 255) - 128);
            r = (r - (long)dg) >> 8;
            Bt[((size_t)(((d * 9 + k) * 4 + ks) * 4 + Nt)) * 1024 + l * 16 + bp] = (s8)dg;
        }
    }
}

// ---------------------------------------------------------------------------
// K2: FUSED conv2+bn2+IF2+pool, TWO timesteps per phase (r18, 152us).
// ---------------------------------------------------------------------------
__global__ __launch_bounds__(512, 2) void k2_conv2_if_pool(
    const u8* __restrict__ p1s, const s8* __restrict__ Bt,
    const float* __restrict__ g2, const float* __restrict__ bb2,
    const float* __restrict__ m2, const float* __restrict__ v2,
    u8* __restrict__ z2)
{
    int bx = blockIdx.x;          // 512 = b*4 + cq
    int b = bx >> 2, cq = bx & 3;

    int tid = threadIdx.x;
    int lane = tid & 63;
    int lane32 = lane & 31;
    int khalf = (lane >> 5) << 4;
    int w = __builtin_amdgcn_readfirstlane(tid >> 6);  // wave 0..7 = M tile
    int rhi = (lane >> 5) * 4;

    __shared__ u8 sp[2][P1S_PITCH];     // two spike planes (t-pair)
    __shared__ u8 bbuf[2][36864];       // B slab dbuf: 9 taps x 4 digits
    __shared__ u8 sbuf[2][NPIX2 * 32];  // spike bytes for pooling (t-pair)

    // zero the dummy row 196 of both planes (never rewritten)
    if (tid < 16) {
        int pl = tid >> 3;
        *(uint4*)(sp[pl] + 196 * 128 + (tid & 7) * 16) = make_uint4(0u, 0u, 0u, 0u);
    }

    // bn2 constants (co = cq*32 + lane32)
    int co = cq * 32 + lane32;
    double binv  = (double)g2[co] / sqrt((double)v2[co] + 1e-5);
    double bbeta = (double)bb2[co] - (double)m2[co] * binv;

    // packed per-lane tap addresses (shared by both t); 196 = zero row
    int p = w * 32 + lane32;
    int valid = (p < NPIX2);
    int pe = valid ? p : 0;
    int py = pe / 14, px = pe - py * 14;
    int comb[9];
#pragma unroll
    for (int tap = 0; tap < 9; ++tap) {
        int dy = tap / 3 - 1, dx = tap - (tap / 3) * 3 - 1;
        int ny = py + dy, nx = px + dx;
        int ok = valid & (ny >= 0) & (ny < 14) & (nx >= 0) & (nx < 14);
        int pixn = ok ? (ny * 14 + nx) : 196;
        comb[tap] = pixn * 128 + ((pixn & 7) << 4);
    }

    // stage full B slab for k-slice ks -> bbuf[bufsel]: 36 frags over 8 waves
    auto stageB = [&](int ks, int bufsel) {
#pragma unroll
        for (int i = 0; i < 5; ++i) {
            int f = w + i * 8;        // 0..39, f = d*9+tap composite
            if (f < 36) {
                GLOAD16(Bt + ((size_t)((f * 4 + ks) * 4 + cq)) * 1024 + lane * 16,
                        bbuf[bufsel] + f * 1024);
            }
        }
    };

    // prologue: t=0,1 spike planes + slab ks=0 -> buf 0
    {
        const u8* s0 = p1s + (size_t)b * P1S_PITCH;
        const u8* s1 = p1s + (size_t)(BATCH + b) * P1S_PITCH;
        for (int i = tid; i < 1568; i += 512) GLOAD16(s0 + i * 16, sp[0] + i * 16);
        for (int i = tid; i < 1568; i += 512) GLOAD16(s1 + i * 16, sp[1] + i * 16);
        stageB(0, 0);
    }
    __syncthreads();

    double vst[16];
#pragma unroll
    for (int r = 0; r < 16; ++r) vst[r] = 0.0;

#pragma unroll 1
    for (int tg = 0; tg < 4; ++tg) {
        v16i acc[2][4];
#pragma unroll
        for (int h = 0; h < 2; ++h)
#pragma unroll
            for (int d = 0; d < 4; ++d)
#pragma unroll
                for (int r = 0; r < 16; ++r) acc[h][d][r] = 0;

#pragma unroll 1
        for (int ks = 0; ks < 4; ++ks) {
            int cur = ks & 1;
            // prefetch next slab (periodic mod 4; final prefetch harmless)
            stageB((ks + 1) & 3, cur ^ 1);

            int K = ks * 32 + khalf;
            const u8* bbp = bbuf[cur];
#pragma unroll
            for (int tap = 0; tap < 9; ++tap) {
                v4i A0 = *(const v4i*)(sp[0] + (comb[tap] ^ K));
                v4i A1 = *(const v4i*)(sp[1] + (comb[tap] ^ K));
#pragma unroll
                for (int d = 0; d < 4; ++d) {
                    v4i B = *(const v4i*)(bbp + (d * 9 + tap) * 1024 + lane * 16);
                    acc[0][d] = __builtin_amdgcn_mfma_i32_32x32x32_i8(A0, B, acc[0][d], 0, 0, 0);
                    acc[1][d] = __builtin_amdgcn_mfma_i32_32x32x32_i8(A1, B, acc[1][d], 0, 0, 0);
                }
            }
            __syncthreads();   // protects bbuf reuse + drains prefetch
        }

        // sp reads done for this pair; stage next pair's spike planes
        if (tg + 1 < 4) {
            const u8* sn0 = p1s + (size_t)((2 * tg + 2) * BATCH + b) * P1S_PITCH;
            const u8* sn1 = p1s + (size_t)((2 * tg + 3) * BATCH + b) * P1S_PITCH;
            for (int i = tid; i < 1568; i += 512) GLOAD16(sn0 + i * 16, sp[0] + i * 16);
            for (int i = tid; i < 1568; i += 512) GLOAD16(sn1 + i * 16, sp[1] + i * 16);
        }

        // merge digits (exact f64 Horner) + bn2 + IF steps: t0 then t1, same vst
#pragma unroll
        for (int h = 0; h < 2; ++h) {
#pragma unroll
            for (int r = 0; r < 16; ++r) {
                double carry = (((double)acc[h][3][r] * 256.0 + (double)acc[h][2][r]) * 256.0
                               + (double)acc[h][1][r]) * 256.0 + (double)acc[h][0][r];
                int pix = w * 32 + (r & 3) + 8 * (r >> 2) + rhi;
                double hin = carry * W2_INVSCALE * binv + bbeta;
                double hv = vst[r] + hin;
                int s = (hv >= 1.0);
                vst[r] = s ? 0.0 : hv;
                if (pix < NPIX2) sbuf[h][pix * 32 + lane32] = (u8)s;
            }
        }
        __syncthreads();

        // 2x2 pool for both t -> z2[kb][tb][32] (u32 sbuf reads)
        for (int j = tid; j < 2 * 49 * 8; j += 512) {
            int h = (j >= 49 * 8);
            int jj = j - h * (49 * 8);
            int w49 = jj >> 3, c4 = jj & 7;
            int wy = w49 / 7, wx = w49 - wy * 7;
            int p0 = (2 * wy) * 14 + 2 * wx;
            u32 s4 = *(const u32*)(sbuf[h] + p0 * 32 + c4 * 4)
                   | *(const u32*)(sbuf[h] + (p0 + 1) * 32 + c4 * 4)
                   | *(const u32*)(sbuf[h] + (p0 + 14) * 32 + c4 * 4)
                   | *(const u32*)(sbuf[h] + (p0 + 15) * 32 + c4 * 4);
            int tb = (2 * tg + h) * BATCH + b;
#pragma unroll
            for (int e = 0; e < 4; ++e) {
                int c32 = c4 * 4 + e;
                int i2 = (cq * 32 + c32) * 49 + w49;
                z2[((size_t)(i2 >> 5) * TB + tb) * 32 + (i2 & 31)] = (u8)((s4 >> (8 * e)) & 1u);
            }
        }
        __syncthreads();   // drains sp staging before next pair's A reads
    }
}

// ---------------------------------------------------------------------------
// K4w: quantize fc1 weights to 4 signed base-256 digits at scale 2^33.
// Layout Wd1[d][kb][o][32] i8.
// ---------------------------------------------------------------------------
__global__ __launch_bounds__(256) void k4w_quant(
    const float* __restrict__ fw, s8* __restrict__ Wd1)
{
    int g = blockIdx.x * 256 + threadIdx.x;   // kb*2048 + o
    if (g >= FC1_KB * FC1_OUT) return;
    int o = g & 2047, kb = g >> 11;

    u32 tmp[FC1_DIGITS][8];
#pragma unroll
    for (int d = 0; d < FC1_DIGITS; ++d)
#pragma unroll
        for (int q = 0; q < 8; ++q) tmp[d][q] = 0;

#pragma unroll
    for (int j = 0; j < 32; ++j) {
        double wd = (double)fw[(size_t)o * FC1_IN + kb * 32 + j] * FC1_SCALE;
        long r = (long)llrint(wd);
#pragma unroll
        for (int d = 0; d < FC1_DIGITS; ++d) {
            int dg = (int)(((r + 128) & 255) - 128);
            r = (r - (long)dg) >> 8;
            tmp[d][j >> 2] |= (u32)(dg & 255) << ((j & 3) * 8);
        }
    }
#pragma unroll
    for (int d = 0; d < FC1_DIGITS; ++d) {
        u32* dst = (u32*)(Wd1 + (((size_t)d * FC1_KB + kb) * FC1_OUT + o) * 32);
        *(uint4*)dst       = make_uint4(tmp[d][0], tmp[d][1], tmp[d][2], tmp[d][3]);
        *(uint4*)(dst + 4) = make_uint4(tmp[d][4], tmp[d][5], tmp[d][6], tmp[d][7]);
    }
}

// ---------------------------------------------------------------------------
// K4: fc1 via i8 MFMA, digit-split -> i32 partials. Grid 256 = mt8 x (nt8 x d4),
// bx = mt*32 + ntd so bx%8 = ntd%8 (same-B blocks colocate per XCD).
// Block 512 thr = 8 waves (2wm x 4wn), tile 128tb x 256o, wave 64x64 (2x2 sub).
// DEEPER PHASES: 49 phases x 4 kb (was 98 x 2) -> half the barriers/drains;
// 96KB LDS dbuf (still 1 block/CU at grid 256). Fragment-order staging.
// ---------------------------------------------------------------------------
__global__ __launch_bounds__(512, 2) void k4_fc1_i8(
    const u8* __restrict__ z2, const s8* __restrict__ Wd1,
    int* __restrict__ Hpart)
{
    __shared__ u8 stg[2 * 49152];   // [buf][A 16KB | B 32KB]

    int bx = blockIdx.x;
    int ntd = bx & 31, mt = bx >> 5;
    int nt = ntd >> 2, d = ntd & 3;

    int tid = threadIdx.x;
    int lane = tid & 63, lane32 = lane & 31;
    int half16 = (lane >> 5) << 4;
    int wv = __builtin_amdgcn_readfirstlane(tid >> 6);  // 0..7
    int wm = wv >> 2, wn = wv & 3;

    int tb0 = mt * 128, o0 = nt * 256;

    v16i acc00, acc01, acc10, acc11;
#pragma unroll
    for (int r = 0; r < 16; ++r) { acc00[r] = 0; acc01[r] = 0; acc10[r] = 0; acc11[r] = 0; }

    auto stage = [&](int q, int buf) {
        int kbg0 = q * 4;
        for (int i = wv; i < 48; i += 8) {
            if (i < 16) {
                int kbr = i >> 2, sub = i & 3;
                GLOAD16(z2 + ((size_t)(kbg0 + kbr) * TB + tb0 + sub * 32 + lane32) * 32 + half16,
                        stg + buf * 49152 + i * 1024);
            } else {
                int j = i - 16;
                int kbr = j >> 3, osub = j & 7;
                GLOAD16(Wd1 + (((size_t)d * FC1_KB + kbg0 + kbr) * FC1_OUT + o0 + osub * 32 + lane32) * 32 + half16,
                        stg + buf * 49152 + 16384 + j * 1024);
            }
        }
    };

    stage(0, 0);
    __syncthreads();

#pragma unroll 1
    for (int q = 0; q < 49; ++q) {
        int buf = q & 1;
        if (q + 1 < 49) stage(q + 1, buf ^ 1);
        const u8* A_ = stg + buf * 49152;
        const u8* B_ = A_ + 16384;
#pragma unroll
        for (int kbr = 0; kbr < 4; ++kbr) {
            v4i A0 = *(const v4i*)(A_ + (kbr * 4 + wm * 2 + 0) * 1024 + lane * 16);
            v4i A1 = *(const v4i*)(A_ + (kbr * 4 + wm * 2 + 1) * 1024 + lane * 16);
            v4i B0 = *(const v4i*)(B_ + (kbr * 8 + wn * 2 + 0) * 1024 + lane * 16);
            v4i B1 = *(const v4i*)(B_ + (kbr * 8 + wn * 2 + 1) * 1024 + lane * 16);
            acc00 = __builtin_amdgcn_mfma_i32_32x32x32_i8(A0, B0, acc00, 0, 0, 0);
            acc01 = __builtin_amdgcn_mfma_i32_32x32x32_i8(A0, B1, acc01, 0, 0, 0);
            acc10 = __builtin_amdgcn_mfma_i32_32x32x32_i8(A1, B0, acc10, 0, 0, 0);
            acc11 = __builtin_amdgcn_mfma_i32_32x32x32_i8(A1, B1, acc11, 0, 0, 0);
        }
        __syncthreads();
    }

    int rhi = (lane >> 5) << 2;
    int* Hd = Hpart + (size_t)d * TB * FC1_OUT;
#pragma unroll
    for (int r = 0; r < 16; ++r) {
        int row = (r & 3) + 8 * (r >> 2) + rhi;
        size_t b0 = (size_t)(tb0 + wm * 64 + row) * FC1_OUT + o0 + wn * 64 + lane32;
        Hd[b0]                             = acc00[r];
        Hd[b0 + 32]                        = acc01[r];
        Hd[b0 + (size_t)32 * FC1_OUT]      = acc10[r];
        Hd[b0 + (size_t)32 * FC1_OUT + 32] = acc11[r];
    }
}

// ---------------------------------------------------------------------------
// K5: combine digit partials (exact, c < 2^44) + IF over T -> s3
// ---------------------------------------------------------------------------
__global__ __launch_bounds__(256) void k5_if3(
    const int* __restrict__ Hpart, u8* __restrict__ s3)
{
    int g = blockIdx.x * 256 + threadIdx.x;   // 128*2048
    int b = g >> 11;
    int o = g & 2047;
    double v = 0.0;
#pragma unroll
    for (int t = 0; t < 8; ++t) {
        size_t idx = (size_t)(t * BATCH + b) * FC1_OUT + o;
        long c = 0;
#pragma unroll
        for (int d = 0; d < FC1_DIGITS; ++d)
            c += ((long)Hpart[(size_t)d * TB * FC1_OUT + idx]) << (8 * d);
        double h = v + (double)c * FC1_INVSCALE;
        int s = (h >= 1.0);
        v = s ? 0.0 : h;
        s3[idx] = (u8)s;
    }
}

// ---------------------------------------------------------------------------
// K6: fc2 h4[tb][16] = sum_i s3[tb][i]*fw2[o][i], f64. 256 thr, K-quarters.
// ---------------------------------------------------------------------------
__global__ __launch_bounds__(256) void k6_fc2(
    const u8* __restrict__ s3, const float* __restrict__ fw2,
    double* __restrict__ h4)
{
    int tb = blockIdx.x;
    int tid = threadIdx.x;
    int w = tid >> 6, lane = tid & 63;
    __shared__ double red[4][16];

    double acc[10];
#pragma unroll
    for (int o = 0; o < 10; ++o) acc[o] = 0.0;

#pragma unroll
    for (int it = 0; it < 8; ++it) {
        int i = w * 512 + it * 64 + lane;
        double zd = (double)s3[(size_t)tb * FC1_OUT + i];
#pragma unroll
        for (int o = 0; o < 10; ++o)
            acc[o] += zd * (double)fw2[o * FC1_OUT + i];
    }
#pragma unroll
    for (int o = 0; o < 10; ++o) {
#pragma unroll
        for (int off = 32; off >= 1; off >>= 1)
            acc[o] += __shfl_down(acc[o], off);
    }
    if (lane == 0) {
#pragma unroll
        for (int o = 0; o < 10; ++o) red[w][o] = acc[o];
    }
    __syncthreads();
    if (tid < 10)
        h4[(size_t)tb * 16 + tid] = red[0][tid] + red[1][tid] + red[2][tid] + red[3][tid];
}

// ---------------------------------------------------------------------------
// K7: IF over T on h4 + mean -> out[b][10] f32
// ---------------------------------------------------------------------------
__global__ __launch_bounds__(256) void k7_if4_mean(
    const double* __restrict__ h4, float* __restrict__ out)
{
    int g = blockIdx.x * 256 + threadIdx.x;
    if (g >= BATCH * FC2_OUT) return;
    int b = g / 10;
    int o = g - b * 10;
    double v = 0.0; int cnt = 0;
#pragma unroll
    for (int t = 0; t < 8; ++t) {
        double h = v + h4[(size_t)(t * BATCH + b) * 16 + o];
        int s = (h >= 1.0);
        cnt += s;
        v = s ? 0.0 : h;
    }
    out[b * 10 + o] = (float)cnt * 0.125f;
}

// ---------------------------------------------------------------------------
extern "C" void kernel_launch(void* const* d_in, const int* in_sizes, int n_in,
                              void* d_out, int out_size, void* d_ws, size_t ws_size,
                              hipStream_t stream)
{
    const float* x   = (const float*)d_in[0];
    const float* w1  = (const float*)d_in[1];
    const float* g1  = (const float*)d_in[2];
    const float* b1  = (const float*)d_in[3];
    const float* m1  = (const float*)d_in[4];
    const float* v1  = (const float*)d_in[5];
    const float* w2  = (const float*)d_in[6];
    const float* g2  = (const float*)d_in[7];
    const float* b2  = (const float*)d_in[8];
    const float* m2  = (const float*)d_in[9];
    const float* v2  = (const float*)d_in[10];
    const float* fw1 = (const float*)d_in[11];
    const float* fw2 = (const float*)d_in[12];
    float* out = (float*)d_out;

    char* ws = (char*)d_ws;
    size_t off = 0;
    auto alloc = [&](size_t sz) { size_t o = off; off = (off + sz + 255) & ~(size_t)255; return o; };

    size_t o_p1 = alloc((size_t)TB * P1S_PITCH);                         // 25.8 MB
    size_t o_z  = alloc((size_t)TB * FC1_IN);                            // 6.4 MB
    size_t o_s3 = alloc((size_t)TB * FC1_OUT);                           // 2.1 MB
    size_t o_h4 = alloc((size_t)TB * 16 * 8);                            // 128 KB
    size_t o_wd = alloc((size_t)W2_DIGITS * 9 * CH * CH);                // 590 KB
    size_t o_w1 = alloc((size_t)FC1_DIGITS * FC1_KB * FC1_OUT * 32);     // 51.4 MB
    size_t o_hp = alloc((size_t)FC1_DIGITS * TB * FC1_OUT * 4);          // 33.6 MB
    (void)ws_size;

    u8*     p1s    = (u8*)(ws + o_p1);
    u8*     z2     = (u8*)(ws + o_z);
    u8*     s3     = (u8*)(ws + o_s3);
    double* h4     = (double*)(ws + o_h4);
    s8*     Bt     = (s8*)(ws + o_wd);
    s8*     Wd1    = (s8*)(ws + o_w1);
    int*    Hpart  = (int*)(ws + o_hp);

    k2w_quant<<<dim3((CH * CH + 255) / 256), dim3(256), 0, stream>>>(w2, Bt);

    k4w_quant<<<dim3((FC1_KB * FC1_OUT + 255) / 256), dim3(256), 0, stream>>>(
        fw1, Wd1);

    k1_conv1_if_pool<<<dim3(512), dim3(256), 0, stream>>>(
        x, w1, g1, b1, m1, v1, p1s);

    k2_conv2_if_pool<<<dim3(512), dim3(512), 0, stream>>>(
        p1s, Bt, g2, b2, m2, v2, z2);

    k4_fc1_i8<<<dim3(256), dim3(512), 0, stream>>>(z2, Wd1, Hpart);

    k5_if3<<<dim3(BATCH * FC1_OUT / 256), dim3(256), 0, stream>>>(Hpart, s3);

    k6_fc2<<<dim3(TB), dim3(256), 0, stream>>>(s3, fw2, h4);

    k7_if4_mean<<<dim3((BATCH * FC2_OUT + 255) / 256), dim3(256), 0, stream>>>(h4, out);
}